// Round 15
// baseline (838.503 us; speedup 1.0000x reference)
//
#include <hip/hip_runtime.h>
#include <math.h>

#define NN 100000
#define NE 1600000
#define DIN 256
#define HD 64
#define OUTD 32
#define EMBD 128
#define SLOPE 0.2f
#define AST 68
#define NT ((NN + 63) / 64)
#define SCHUNK 1024
#define SNBLK ((NN + SCHUNK - 1) / SCHUNK)   // 98
#define NB ((NN + 63) / 64)                  // 1563 buckets for CSR fill

typedef __attribute__((ext_vector_type(8))) short bf16x8;
typedef __attribute__((ext_vector_type(8))) unsigned short u16x8;
typedef __attribute__((ext_vector_type(4))) float f32x4;

__device__ __forceinline__ float lrelu(float x) { return x > 0.f ? x : SLOPE * x; }
__device__ __forceinline__ ushort f2b(float f) {
    unsigned u = __float_as_uint(f);
    return (ushort)((u + 0x7FFFu + ((u >> 16) & 1u)) >> 16);  // RTNE fp32->bf16
}
__device__ __forceinline__ float b2f(ushort v) { return __uint_as_float(((unsigned)v) << 16); }

// ================= CSR build =================
__global__ void k_count(const int* __restrict__ dst, int* __restrict__ cnt) {
    int i = blockIdx.x * blockDim.x + threadIdx.x;
    if (i < NE) atomicAdd(&cnt[dst[i]], 1);
}

__global__ __launch_bounds__(256) void k_scan1(const int* __restrict__ cnt,
                                               int* __restrict__ rowptr,
                                               int* __restrict__ blksum) {
    __shared__ int ts[256];
    int base = blockIdx.x * SCHUNK + threadIdx.x * 4;
    int v0 = 0, v1 = 0, v2 = 0, v3 = 0;
    if (base < NN)     v0 = cnt[base];
    if (base + 1 < NN) v1 = cnt[base + 1];
    if (base + 2 < NN) v2 = cnt[base + 2];
    if (base + 3 < NN) v3 = cnt[base + 3];
    int s = v0 + v1 + v2 + v3;
    ts[threadIdx.x] = s;
    __syncthreads();
    for (int off = 1; off < 256; off <<= 1) {
        int w = (threadIdx.x >= off) ? ts[threadIdx.x - off] : 0;
        __syncthreads();
        ts[threadIdx.x] += w;
        __syncthreads();
    }
    int excl = ts[threadIdx.x] - s;
    if (base < NN)     rowptr[base]     = excl;
    if (base + 1 < NN) rowptr[base + 1] = excl + v0;
    if (base + 2 < NN) rowptr[base + 2] = excl + v0 + v1;
    if (base + 3 < NN) rowptr[base + 3] = excl + v0 + v1 + v2;
    if (threadIdx.x == 255) blksum[blockIdx.x] = ts[255];
}

__global__ __launch_bounds__(128) void k_scan2(int* __restrict__ blksum) {
    __shared__ int ts[128];
    int t = threadIdx.x;
    int v = (t < SNBLK) ? blksum[t] : 0;
    ts[t] = v;
    __syncthreads();
    for (int off = 1; off < 128; off <<= 1) {
        int w = (t >= off) ? ts[t - off] : 0;
        __syncthreads();
        ts[t] += w;
        __syncthreads();
    }
    if (t < SNBLK) blksum[t] = ts[t] - v;
}

// adds block offsets; emits invdeg and per-bucket cursors (bucket = node>>6)
__global__ void k_scan3(const int* __restrict__ blksum, const int* __restrict__ cnt,
                        int* __restrict__ rowptr, int* __restrict__ bcursor,
                        float* __restrict__ invdeg) {
    int i = blockIdx.x * blockDim.x + threadIdx.x;
    if (i < NN) {
        int v = rowptr[i] + blksum[i >> 10];
        rowptr[i] = v;
        if ((i & 63) == 0) bcursor[i >> 6] = v;
        invdeg[i] = 1.0f / fmaxf((float)cnt[i], 1.0f);
    }
    if (i == 0) rowptr[NN] = NE;
}

// phase A: scatter (src,dst) pairs into per-bucket regions (clustered writes)
__global__ void k_fillA(const int* __restrict__ src, const int* __restrict__ dst,
                        int* __restrict__ bcursor, int2* __restrict__ pairbuf) {
    int i = blockIdx.x * blockDim.x + threadIdx.x;
    if (i >= NE) return;
    int s = src[i], d = dst[i];
    int pos = atomicAdd(&bcursor[d >> 6], 1);
    pairbuf[pos] = make_int2(s, d);
}

// phase B: one block per bucket; LDS cursors; colsrc writes land in a ~4KB window
__global__ __launch_bounds__(256) void k_fillB(const int* __restrict__ rowptr,
                                               const int2* __restrict__ pairbuf,
                                               int* __restrict__ colsrc) {
    __shared__ int lcur[64];
    int b = blockIdx.x;
    int nb0 = b * 64;
    int t = threadIdx.x;
    if (t < 64) {
        int node = nb0 + t;
        lcur[t] = (node < NN) ? rowptr[node] : NE;
    }
    __syncthreads();
    int start = rowptr[nb0];
    int end = (nb0 + 64 <= NN) ? rowptr[nb0 + 64] : NE;
    for (int i = start + t; i < end; i += 256) {
        int2 p = pairbuf[i];
        int pos = atomicAdd(&lcur[p.y & 63], 1);
        colsrc[pos] = p.x;
    }
}

// ================= fp32 tiled GEMM helpers (R12 form) =================
__device__ __forceinline__ void stageA(const float* __restrict__ g, int nbase, int ldg, int koff,
                                       float (*As)[AST]) {
    for (int i = threadIdx.x; i < 1024; i += 256) {
        int m = i >> 4, k4 = (i & 15) << 2;
        int row = nbase + m;
        if (row >= NN) row = NN - 1;
        *(float4*)&As[m][k4] = *(const float4*)&g[(size_t)row * ldg + koff + k4];
    }
}
__device__ __forceinline__ void stageW(const float* __restrict__ g, float* Ws) {
    for (int i = threadIdx.x; i < 1024; i += 256) ((float4*)Ws)[i] = ((const float4*)g)[i];
}
__device__ __forceinline__ void stageWcols(const float* __restrict__ g, int ldg, int coff,
                                           float* Ws) {
    for (int i = threadIdx.x; i < 1024; i += 256) {
        int r = i >> 4, c4 = (i & 15) << 2;
        *(float4*)&Ws[r * 64 + c4] = *(const float4*)&g[r * ldg + coff + c4];
    }
}
__device__ __forceinline__ void mac16v(const float (*As)[AST], const float* __restrict__ Ws,
                                       float (*acc)[4], int tr, int tc) {
#pragma unroll 4
    for (int k4 = 0; k4 < 64; k4 += 4) {
        float4 a0 = *(const float4*)&As[tr * 4 + 0][k4];
        float4 a1 = *(const float4*)&As[tr * 4 + 1][k4];
        float4 a2 = *(const float4*)&As[tr * 4 + 2][k4];
        float4 a3 = *(const float4*)&As[tr * 4 + 3][k4];
#pragma unroll
        for (int j = 0; j < 4; j++) {
            float4 w = *(const float4*)&Ws[(k4 + j) * 64 + tc * 4];
            float e0 = (&a0.x)[j], e1 = (&a1.x)[j], e2 = (&a2.x)[j], e3 = (&a3.x)[j];
            acc[0][0] += e0 * w.x; acc[0][1] += e0 * w.y; acc[0][2] += e0 * w.z; acc[0][3] += e0 * w.w;
            acc[1][0] += e1 * w.x; acc[1][1] += e1 * w.y; acc[1][2] += e1 * w.z; acc[1][3] += e1 * w.w;
            acc[2][0] += e2 * w.x; acc[2][1] += e2 * w.y; acc[2][2] += e2 * w.z; acc[2][3] += e2 * w.w;
            acc[3][0] += e3 * w.x; acc[3][1] += e3 * w.y; acc[3][2] += e3 * w.z; acc[3][3] += e3 * w.w;
        }
    }
}

// ================= n2v projection (fp32, R12 form) =================
__global__ __launch_bounds__(256) void k_n2vp_t(const float* __restrict__ n2v,
                                                const float* __restrict__ w,
                                                const float* __restrict__ b,
                                                float* __restrict__ n2vp) {
    __shared__ float As[64][AST];
    __shared__ float Ws[64 * 64];
    int nbase = blockIdx.x * 64;
    int tc = threadIdx.x & 15, tr = threadIdx.x >> 4;
    float acc[4][4] = {};
    for (int c = 0; c < 2; c++) {
        if (c) __syncthreads();
        stageA(n2v, nbase, EMBD, c * 64, As);
        stageW(w + c * 64 * 64, Ws);
        __syncthreads();
        mac16v(As, Ws, acc, tr, tc);
    }
    float b0 = b[tc * 4], b1 = b[tc * 4 + 1], b2 = b[tc * 4 + 2], b3 = b[tc * 4 + 3];
#pragma unroll
    for (int i = 0; i < 4; i++) {
        int row = nbase + tr * 4 + i;
        if (row < NN) {
            float4 o = {acc[i][0] + b0, acc[i][1] + b1, acc[i][2] + b2, acc[i][3] + b3};
            *(float4*)&n2vp[(size_t)row * HD + tc * 4] = o;
        }
    }
}

// ================= front: bf16 hi/lo split MFMA (R14) =================
__global__ __launch_bounds__(256) void k_front_t(const float* __restrict__ x,
                                                 const float* __restrict__ n2vp,
                                                 const float* __restrict__ ip_w,
                                                 const float* __restrict__ ip_b,
                                                 const float* __restrict__ gate_w,
                                                 const float* __restrict__ gate_b,
                                                 float* __restrict__ h0,
                                                 ushort* __restrict__ h0b) {
    __shared__ ushort Ah[64][40], Al[64][40];
    __shared__ ushort Bih[64][40], Bil[64][40];
    __shared__ ushort Bgh[64][40], Bgl[64][40];
    int nbase = blockIdx.x * 64;
    int tid = threadIdx.x;
    int w = tid >> 6, l = tid & 63;
    int lr = l & 15, lg = l >> 4, lk = lg * 8;
    f32x4 zero = {0.f, 0.f, 0.f, 0.f};
    f32x4 araw[4], ag[4], adel[4];
#pragma unroll
    for (int t = 0; t < 4; t++) { araw[t] = zero; ag[t] = zero; adel[t] = zero; }

    int arow = tid >> 2, ak0 = (tid & 3) << 3;
    int garow = nbase + arow;
    if (garow >= NN) garow = NN - 1;

    for (int c = 0; c < 8; c++) {
        if (c) __syncthreads();
        {
            const float* src = &x[(size_t)garow * DIN + c * 32 + ak0];
            u16x8 th, tl;
#pragma unroll
            for (int u = 0; u < 8; u++) {
                float v = src[u];
                ushort h = f2b(v);
                th[u] = h;
                tl[u] = f2b(v - b2f(h));
            }
            *(u16x8*)&Ah[arow][ak0] = th;
            *(u16x8*)&Al[arow][ak0] = tl;
        }
        {
            const float* pi = &ip_w[(size_t)(c * 32 + w * 8) * 64 + l];
            const float* pg = &gate_w[(size_t)(c * 32 + w * 8) * 64 + l];
            u16x8 ih, il, gh, gl2;
#pragma unroll
            for (int u = 0; u < 8; u++) {
                float v = pi[u * 64];
                ushort h = f2b(v);
                ih[u] = h; il[u] = f2b(v - b2f(h));
                float g = pg[u * 64];
                ushort hg = f2b(g);
                gh[u] = hg; gl2[u] = f2b(g - b2f(hg));
            }
            *(u16x8*)&Bih[l][w * 8] = ih;
            *(u16x8*)&Bil[l][w * 8] = il;
            *(u16x8*)&Bgh[l][w * 8] = gh;
            *(u16x8*)&Bgl[l][w * 8] = gl2;
        }
        __syncthreads();
        bf16x8 ah = *(const bf16x8*)&Ah[w * 16 + lr][lk];
        bf16x8 al = *(const bf16x8*)&Al[w * 16 + lr][lk];
#pragma unroll
        for (int t = 0; t < 4; t++) {
            int col = t * 16 + lr;
            bf16x8 bih = *(const bf16x8*)&Bih[col][lk];
            bf16x8 bil = *(const bf16x8*)&Bil[col][lk];
            bf16x8 bgh = *(const bf16x8*)&Bgh[col][lk];
            bf16x8 bgl = *(const bf16x8*)&Bgl[col][lk];
            f32x4 r = araw[t];
            r = __builtin_amdgcn_mfma_f32_16x16x32_bf16(ah, bih, r, 0, 0, 0);
            r = __builtin_amdgcn_mfma_f32_16x16x32_bf16(ah, bil, r, 0, 0, 0);
            r = __builtin_amdgcn_mfma_f32_16x16x32_bf16(al, bih, r, 0, 0, 0);
            araw[t] = r;
            f32x4 g = ag[t];
            g = __builtin_amdgcn_mfma_f32_16x16x32_bf16(ah, bgh, g, 0, 0, 0);
            g = __builtin_amdgcn_mfma_f32_16x16x32_bf16(ah, bgl, g, 0, 0, 0);
            g = __builtin_amdgcn_mfma_f32_16x16x32_bf16(al, bgh, g, 0, 0, 0);
            ag[t] = g;
        }
    }
    for (int c = 0; c < 2; c++) {
        __syncthreads();
        {
            const float* src = &n2vp[(size_t)garow * HD + c * 32 + ak0];
            u16x8 th, tl;
#pragma unroll
            for (int u = 0; u < 8; u++) {
                float v = src[u];
                ushort h = f2b(v);
                th[u] = h;
                tl[u] = f2b(v - b2f(h));
            }
            *(u16x8*)&Ah[arow][ak0] = th;
            *(u16x8*)&Al[arow][ak0] = tl;
        }
        {
            const float* pi = &ip_w[(size_t)(DIN + c * 32 + w * 8) * 64 + l];
            const float* pg = &gate_w[(size_t)(DIN + c * 32 + w * 8) * 64 + l];
            u16x8 ih, il, gh, gl2;
#pragma unroll
            for (int u = 0; u < 8; u++) {
                float v = pi[u * 64];
                ushort h = f2b(v);
                ih[u] = h; il[u] = f2b(v - b2f(h));
                float g = pg[u * 64];
                ushort hg = f2b(g);
                gh[u] = hg; gl2[u] = f2b(g - b2f(hg));
            }
            *(u16x8*)&Bih[l][w * 8] = ih;
            *(u16x8*)&Bil[l][w * 8] = il;
            *(u16x8*)&Bgh[l][w * 8] = gh;
            *(u16x8*)&Bgl[l][w * 8] = gl2;
        }
        __syncthreads();
        bf16x8 ah = *(const bf16x8*)&Ah[w * 16 + lr][lk];
        bf16x8 al = *(const bf16x8*)&Al[w * 16 + lr][lk];
#pragma unroll
        for (int t = 0; t < 4; t++) {
            int col = t * 16 + lr;
            bf16x8 bih = *(const bf16x8*)&Bih[col][lk];
            bf16x8 bil = *(const bf16x8*)&Bil[col][lk];
            bf16x8 bgh = *(const bf16x8*)&Bgh[col][lk];
            bf16x8 bgl = *(const bf16x8*)&Bgl[col][lk];
            f32x4 r = adel[t];
            r = __builtin_amdgcn_mfma_f32_16x16x32_bf16(ah, bih, r, 0, 0, 0);
            r = __builtin_amdgcn_mfma_f32_16x16x32_bf16(ah, bil, r, 0, 0, 0);
            r = __builtin_amdgcn_mfma_f32_16x16x32_bf16(al, bih, r, 0, 0, 0);
            adel[t] = r;
            f32x4 g = ag[t];
            g = __builtin_amdgcn_mfma_f32_16x16x32_bf16(ah, bgh, g, 0, 0, 0);
            g = __builtin_amdgcn_mfma_f32_16x16x32_bf16(ah, bgl, g, 0, 0, 0);
            g = __builtin_amdgcn_mfma_f32_16x16x32_bf16(al, bgh, g, 0, 0, 0);
            ag[t] = g;
        }
    }
#pragma unroll
    for (int t = 0; t < 4; t++) {
        int col = t * 16 + lr;
        float ib = ip_b[col], gb2 = gate_b[col];
#pragma unroll
        for (int r = 0; r < 4; r++) {
            int row = nbase + w * 16 + lg * 4 + r;
            if (row < NN) {
                float raw = araw[t][r] + ib;
                float sg = 1.f / (1.f + __expf(-(ag[t][r] + gb2)));
                float o = raw + sg * adel[t][r];
                h0[(size_t)row * HD + col] = o;
                h0b[(size_t)row * HD + col] = f2b(o);
            }
        }
    }
}

// ================= gather mean (R12) =================
__global__ void k_gather_mean(const int* __restrict__ rowptr, const int* __restrict__ colsrc,
                              const float* __restrict__ invdeg, const ushort* __restrict__ hb,
                              float* __restrict__ agg) {
    int t = threadIdx.x & 63;
    int lane = t & 31, half = t >> 5;
    int gw = blockIdx.x * (blockDim.x >> 6) + (threadIdx.x >> 6);
    int stride = gridDim.x * (blockDim.x >> 6);
    for (int n = gw; n < NN; n += stride) {
        int bg = rowptr[n], en = rowptr[n + 1];
        float a0 = 0.f, a1 = 0.f;
        int i = bg + half;
        for (; i + 6 < en; i += 8) {
            int sa = colsrc[i], sb = colsrc[i + 2], sc = colsrc[i + 4], sd = colsrc[i + 6];
            ushort2 va = *(const ushort2*)&hb[(size_t)sa * HD + lane * 2];
            ushort2 vb = *(const ushort2*)&hb[(size_t)sb * HD + lane * 2];
            ushort2 vc = *(const ushort2*)&hb[(size_t)sc * HD + lane * 2];
            ushort2 vd = *(const ushort2*)&hb[(size_t)sd * HD + lane * 2];
            a0 += b2f(va.x) + b2f(vb.x) + b2f(vc.x) + b2f(vd.x);
            a1 += b2f(va.y) + b2f(vb.y) + b2f(vc.y) + b2f(vd.y);
        }
        for (; i < en; i += 2) {
            int s = colsrc[i];
            ushort2 v = *(const ushort2*)&hb[(size_t)s * HD + lane * 2];
            a0 += b2f(v.x);
            a1 += b2f(v.y);
        }
        a0 += __shfl_xor(a0, 32);
        a1 += __shfl_xor(a1, 32);
        if (half == 0) {
            float id = invdeg[n];
            float2 o = {a0 * id, a1 * id};
            *(float2*)&agg[(size_t)n * HD + lane * 2] = o;
        }
    }
}

// ================= SAGE combine (R12) =================
__global__ __launch_bounds__(256) void k_sage_t(const float* __restrict__ agg,
                                                const float* __restrict__ h,
                                                const float* __restrict__ wl,
                                                const float* __restrict__ bl,
                                                const float* __restrict__ wr,
                                                float* __restrict__ hout,
                                                ushort* __restrict__ houtb) {
    __shared__ float As[64][AST];
    __shared__ float Ws[64 * 64];
    int nbase = blockIdx.x * 64;
    int tc = threadIdx.x & 15, tr = threadIdx.x >> 4;
    float acc[4][4] = {};
    stageA(agg, nbase, HD, 0, As);
    stageW(wl, Ws);
    __syncthreads();
    mac16v(As, Ws, acc, tr, tc);
    __syncthreads();
    stageA(h, nbase, HD, 0, As);
    stageW(wr, Ws);
    __syncthreads();
    mac16v(As, Ws, acc, tr, tc);
    float b0 = bl[tc * 4], b1 = bl[tc * 4 + 1], b2 = bl[tc * 4 + 2], b3 = bl[tc * 4 + 3];
#pragma unroll
    for (int i = 0; i < 4; i++) {
        int row = nbase + tr * 4 + i;
        if (row < NN) {
            float4 o = {fmaxf(acc[i][0] + b0, 0.f), fmaxf(acc[i][1] + b1, 0.f),
                        fmaxf(acc[i][2] + b2, 0.f), fmaxf(acc[i][3] + b3, 0.f)};
            *(float4*)&hout[(size_t)row * HD + tc * 4] = o;
            ushort4 ob = {f2b(o.x), f2b(o.y), f2b(o.z), f2b(o.w)};
            *(ushort4*)&houtb[(size_t)row * HD + tc * 4] = ob;
        }
    }
}

// ================= GAT transform (R12) =================
__global__ __launch_bounds__(256) void k_gatxh_t(const float* __restrict__ h,
                                                 const float* __restrict__ w,
                                                 const float* __restrict__ att_s,
                                                 const float* __restrict__ att_d,
                                                 ushort* __restrict__ xhb,
                                                 float* __restrict__ a_s,
                                                 float* __restrict__ a_d) {
    __shared__ float As[64][AST];
    __shared__ float Ws[64 * 64];
    int nbase = blockIdx.x * 64;
    int tc = threadIdx.x & 15, tr = threadIdx.x >> 4;
    stageA(h, nbase, HD, 0, As);
#pragma unroll
    for (int half = 0; half < 2; half++) {
        if (half) __syncthreads();
        stageWcols(w, 128, half * 64, Ws);
        __syncthreads();
        float acc[4][4] = {};
        mac16v(As, Ws, acc, tr, tc);
        float as0 = att_s[half * 64 + tc * 4], as1 = att_s[half * 64 + tc * 4 + 1];
        float as2 = att_s[half * 64 + tc * 4 + 2], as3 = att_s[half * 64 + tc * 4 + 3];
        float ad0 = att_d[half * 64 + tc * 4], ad1 = att_d[half * 64 + tc * 4 + 1];
        float ad2 = att_d[half * 64 + tc * 4 + 2], ad3 = att_d[half * 64 + tc * 4 + 3];
#pragma unroll
        for (int i = 0; i < 4; i++) {
            int row = nbase + tr * 4 + i;
            float ps = acc[i][0] * as0 + acc[i][1] * as1 + acc[i][2] * as2 + acc[i][3] * as3;
            float pd = acc[i][0] * ad0 + acc[i][1] * ad1 + acc[i][2] * ad2 + acc[i][3] * ad3;
#pragma unroll
            for (int off = 8; off; off >>= 1) {
                ps += __shfl_xor(ps, off);
                pd += __shfl_xor(pd, off);
            }
            if (row < NN) {
                ushort4 ob = {f2b(acc[i][0]), f2b(acc[i][1]), f2b(acc[i][2]), f2b(acc[i][3])};
                *(ushort4*)&xhb[(size_t)row * 128 + half * 64 + tc * 4] = ob;
                if (tc == 0) {
                    a_s[row * 2 + half] = ps;
                    a_d[row * 2 + half] = pd;
                }
            }
        }
    }
}

// ================= GAT fused (R12) =================
__global__ void k_gat_fused(const int* __restrict__ rowptr, const int* __restrict__ colsrc,
                            const float* __restrict__ a_s, const float* __restrict__ a_d,
                            const ushort* __restrict__ xhb, const float* __restrict__ gb,
                            float* __restrict__ hout) {
    int t = threadIdx.x & 63;
    int lane = t & 31, half = t >> 5;
    int bl4 = (lane & 15) * 4;
    float4 bias4 = *(const float4*)&gb[bl4];
    int gw = blockIdx.x * (blockDim.x >> 6) + (threadIdx.x >> 6);
    int stride = gridDim.x * (blockDim.x >> 6);
    for (int n = gw; n < NN; n += stride) {
        int bg = rowptr[n], en = rowptr[n + 1];
        float ad0 = a_d[n * 2], ad1 = a_d[n * 2 + 1];
        float a0 = 0.f, a1 = 0.f, a2 = 0.f, a3 = 0.f;
        float ss0 = 0.f, ss1 = 0.f;
        int i = bg + half;
        for (; i + 2 < en; i += 4) {
            int sa = colsrc[i], sb = colsrc[i + 2];
            float2 ava = *(const float2*)&a_s[sa * 2];
            float2 avb = *(const float2*)&a_s[sb * 2];
            ushort4 xva = *(const ushort4*)&xhb[(size_t)sa * 128 + lane * 4];
            ushort4 xvb = *(const ushort4*)&xhb[(size_t)sb * 128 + lane * 4];
            float wa0 = __expf(lrelu(ava.x + ad0));
            float wa1 = __expf(lrelu(ava.y + ad1));
            float wb0 = __expf(lrelu(avb.x + ad0));
            float wb1 = __expf(lrelu(avb.y + ad1));
            ss0 += wa0 + wb0;
            ss1 += wa1 + wb1;
            float wsa = (lane < 16) ? wa0 : wa1;
            float wsb = (lane < 16) ? wb0 : wb1;
            a0 += wsa * b2f(xva.x) + wsb * b2f(xvb.x);
            a1 += wsa * b2f(xva.y) + wsb * b2f(xvb.y);
            a2 += wsa * b2f(xva.z) + wsb * b2f(xvb.z);
            a3 += wsa * b2f(xva.w) + wsb * b2f(xvb.w);
        }
        for (; i < en; i += 2) {
            int s = colsrc[i];
            float2 av = *(const float2*)&a_s[s * 2];
            float w0 = __expf(lrelu(av.x + ad0));
            float w1 = __expf(lrelu(av.y + ad1));
            ss0 += w0;
            ss1 += w1;
            float wsel = (lane < 16) ? w0 : w1;
            ushort4 xv = *(const ushort4*)&xhb[(size_t)s * 128 + lane * 4];
            a0 += wsel * b2f(xv.x);
            a1 += wsel * b2f(xv.y);
            a2 += wsel * b2f(xv.z);
            a3 += wsel * b2f(xv.w);
        }
        if (half == 0) {  // self-loop
            float2 av = *(const float2*)&a_s[n * 2];
            float w0 = __expf(lrelu(av.x + ad0));
            float w1 = __expf(lrelu(av.y + ad1));
            ss0 += w0;
            ss1 += w1;
            float wsel = (lane < 16) ? w0 : w1;
            ushort4 xv = *(const ushort4*)&xhb[(size_t)n * 128 + lane * 4];
            a0 += wsel * b2f(xv.x);
            a1 += wsel * b2f(xv.y);
            a2 += wsel * b2f(xv.z);
            a3 += wsel * b2f(xv.w);
        }
        ss0 += __shfl_xor(ss0, 32);
        ss1 += __shfl_xor(ss1, 32);
        a0 += __shfl_xor(a0, 32);
        a1 += __shfl_xor(a1, 32);
        a2 += __shfl_xor(a2, 32);
        a3 += __shfl_xor(a3, 32);
        float r = (lane < 16) ? (0.5f / (ss0 + 1e-16f)) : (0.5f / (ss1 + 1e-16f));
        float v0 = a0 * r, v1 = a1 * r, v2 = a2 * r, v3 = a3 * r;
        float p0 = __shfl_xor(v0, 16);
        float p1 = __shfl_xor(v1, 16);
        float p2 = __shfl_xor(v2, 16);
        float p3 = __shfl_xor(v3, 16);
        if (half == 0 && lane < 16) {
            float4 o = {fmaxf(v0 + p0 + bias4.x, 0.f), fmaxf(v1 + p1 + bias4.y, 0.f),
                        fmaxf(v2 + p2 + bias4.z, 0.f), fmaxf(v3 + p3 + bias4.w, 0.f)};
            *(float4*)&hout[(size_t)n * HD + lane * 4] = o;
        }
    }
}

// ================= final SAGE (R12) =================
__global__ void k_pfin(const float* __restrict__ h, const float* __restrict__ wl,
                       ushort* __restrict__ Pb) {
    __shared__ float sw[HD * OUTD];
    for (int i = threadIdx.x; i < HD * OUTD; i += blockDim.x) sw[i] = wl[i];
    __syncthreads();
    int t = threadIdx.x & 63;
    int c = t & 31, half = t >> 5;
    int gw = blockIdx.x * (blockDim.x >> 6) + (threadIdx.x >> 6);
    int stride = gridDim.x * (blockDim.x >> 6);
    for (int n = gw; n < NN; n += stride) {
        float hv = h[(size_t)n * HD + t];
        float acc = 0.f;
#pragma unroll 8
        for (int i = 0; i < 32; i++) {
            float bb = __shfl(hv, half * 32 + i);
            acc += bb * sw[half * 1024 + i * 32 + c];
        }
        acc += __shfl_xor(acc, 32);
        if (half == 0) Pb[(size_t)n * OUTD + c] = f2b(acc);
    }
}

__global__ void k_final_fused(const int* __restrict__ rowptr, const int* __restrict__ colsrc,
                              const float* __restrict__ invdeg, const ushort* __restrict__ Pb,
                              const float* __restrict__ h, const float* __restrict__ bl,
                              const float* __restrict__ wr, float* __restrict__ out) {
    __shared__ float sw[HD * OUTD];
    for (int i = threadIdx.x; i < HD * OUTD; i += blockDim.x) sw[i] = wr[i];
    __syncthreads();
    int t = threadIdx.x & 63;
    int j = t & 31, half = t >> 5;
    int quarter = t >> 4, lane16 = t & 15;
    float bias = bl[j];
    int gw = blockIdx.x * (blockDim.x >> 6) + (threadIdx.x >> 6);
    int stride = gridDim.x * (blockDim.x >> 6);
    for (int n = gw; n < NN; n += stride) {
        int bg = rowptr[n], en = rowptr[n + 1];
        float a0 = 0.f, a1 = 0.f;
        int i = bg + quarter;
        for (; i + 4 < en; i += 8) {
            int sa = colsrc[i], sb = colsrc[i + 4];
            ushort2 va = *(const ushort2*)&Pb[(size_t)sa * OUTD + lane16 * 2];
            ushort2 vb = *(const ushort2*)&Pb[(size_t)sb * OUTD + lane16 * 2];
            a0 += b2f(va.x) + b2f(vb.x);
            a1 += b2f(va.y) + b2f(vb.y);
        }
        for (; i < en; i += 4) {
            int s = colsrc[i];
            ushort2 v = *(const ushort2*)&Pb[(size_t)s * OUTD + lane16 * 2];
            a0 += b2f(v.x);
            a1 += b2f(v.y);
        }
        a0 += __shfl_xor(a0, 32);
        a1 += __shfl_xor(a1, 32);
        a0 += __shfl_xor(a0, 16);
        a1 += __shfl_xor(a1, 16);
        float hv = h[(size_t)n * HD + t];
        float o = 0.f;
#pragma unroll 8
        for (int i2 = 0; i2 < 32; i2++) {
            float bb = __shfl(hv, half * 32 + i2);
            o += bb * sw[half * 1024 + i2 * 32 + j];
        }
        o += __shfl_xor(o, 32);
        float ga = __shfl(a0, j >> 1);
        float gb_ = __shfl(a1, j >> 1);
        float gv = (j & 1) ? gb_ : ga;
        if (half == 0) out[(size_t)n * OUTD + j] = gv * invdeg[n] + bias + o;
    }
}

// ================= launch =================
extern "C" void kernel_launch(void* const* d_in, const int* in_sizes, int n_in,
                              void* d_out, int out_size, void* d_ws, size_t ws_size,
                              hipStream_t stream) {
    const float* x      = (const float*)d_in[0];
    const int*   eidx   = (const int*)d_in[1];
    const float* n2v    = (const float*)d_in[2];
    const float* n2v_w  = (const float*)d_in[3];
    const float* n2v_b  = (const float*)d_in[4];
    const float* ip_w   = (const float*)d_in[5];
    const float* ip_b   = (const float*)d_in[6];
    const float* gate_w = (const float*)d_in[7];
    const float* gate_b = (const float*)d_in[8];
    const float* s0_wl  = (const float*)d_in[9];
    const float* s0_bl  = (const float*)d_in[10];
    const float* s0_wr  = (const float*)d_in[11];
    const float* s1_wl  = (const float*)d_in[12];
    const float* s1_bl  = (const float*)d_in[13];
    const float* s1_wr  = (const float*)d_in[14];
    const float* gat_w  = (const float*)d_in[15];
    const float* att_s  = (const float*)d_in[16];
    const float* att_d  = (const float*)d_in[17];
    const float* gat_b  = (const float*)d_in[18];
    const float* f_wl   = (const float*)d_in[19];
    const float* f_bl   = (const float*)d_in[20];
    const float* f_wr   = (const float*)d_in[21];

    const int* src = eidx;
    const int* dst = eidx + NE;

    // ---- workspace ----
    float*  ws     = (float*)d_ws;
    float*  invdeg = ws;                         // N
    float*  S1     = invdeg + NN;                // 64N  (h1, h3)
    float*  S2     = S1 + (size_t)NN * HD;       // 64N  (h0, h2)
    float*  SA     = S2 + (size_t)NN * HD;       // 64N  (n2vp / agg)
    float*  a_s    = SA + (size_t)NN * HD;       // 2N
    float*  a_d    = a_s + (size_t)NN * 2;       // 2N
    ushort* Pb     = (ushort*)(a_d + (size_t)NN * 2);   // 32N ushort
    ushort* hb     = Pb + (size_t)NN * OUTD;            // 64N ushort
    ushort* xhb    = hb + (size_t)NN * HD;              // 128N ushort
    int*    cnt    = (int*)(xhb + (size_t)NN * 128);    // N
    int*    rowptr = cnt + NN;                   // N+1
    int*    bcursor = rowptr + NN + 1;           // NB
    int*    blksum = bcursor + NB;               // 128
    int*    colsrc = blksum + 128;               // NE

    int2* pairbuf = (int2*)xhb;  // alias: pairbuf (12.8MB) lives in xhb region (25.6MB),
                                 // used only during CSR fill, before any xhb write

    float* n2vp = SA;
    float* agg  = SA;
    float* out  = (float*)d_out;

    const int BT = 256;
    dim3 b128(128), b256(BT);
    int eblk = (NE + BT - 1) / BT;
    int nblk = (NN + BT - 1) / BT;

    // ---- CSR ----
    hipMemsetAsync(cnt, 0, (size_t)NN * 4, stream);
    k_count<<<eblk, b256, 0, stream>>>(dst, cnt);
    k_scan1<<<SNBLK, b256, 0, stream>>>(cnt, rowptr, blksum);
    k_scan2<<<1, b128, 0, stream>>>(blksum);
    k_scan3<<<nblk, b256, 0, stream>>>(blksum, cnt, rowptr, bcursor, invdeg);
    k_fillA<<<eblk, b256, 0, stream>>>(src, dst, bcursor, pairbuf);
    k_fillB<<<NB, b256, 0, stream>>>(rowptr, pairbuf, colsrc);

    // ---- front ----
    k_n2vp_t<<<NT, b256, 0, stream>>>(n2v, n2v_w, n2v_b, n2vp);
    k_front_t<<<NT, b256, 0, stream>>>(x, n2vp, ip_w, ip_b, gate_w, gate_b, S2, hb);

    // ---- SAGE 0: S2 -> S1 ----
    k_gather_mean<<<2048, b256, 0, stream>>>(rowptr, colsrc, invdeg, hb, agg);
    k_sage_t<<<NT, b256, 0, stream>>>(agg, S2, s0_wl, s0_bl, s0_wr, S1, hb);

    // ---- SAGE 1: S1 -> S2 ----
    k_gather_mean<<<2048, b256, 0, stream>>>(rowptr, colsrc, invdeg, hb, agg);
    k_sage_t<<<NT, b256, 0, stream>>>(agg, S1, s1_wl, s1_bl, s1_wr, S2, hb);

    // ---- GAT: S2 -> S1 ----
    k_gatxh_t<<<NT, b256, 0, stream>>>(S2, gat_w, att_s, att_d, xhb, a_s, a_d);
    k_gat_fused<<<2048, b256, 0, stream>>>(rowptr, colsrc, a_s, a_d, xhb, gat_b, S1);

    // ---- final SAGE: S1 -> out ----
    k_pfin<<<2048, b256, 0, stream>>>(S1, f_wl, Pb);
    k_final_fused<<<2048, b256, 0, stream>>>(rowptr, colsrc, invdeg, Pb, S1, f_bl, f_wr, out);
}

// Round 16
// 695.668 us; speedup vs baseline: 1.2053x; 1.2053x over previous
//
#include <hip/hip_runtime.h>
#include <math.h>

#define NN 100000
#define NE 1600000
#define DIN 256
#define HD 64
#define OUTD 32
#define EMBD 128
#define SLOPE 0.2f
#define AST 68
#define NT ((NN + 63) / 64)
#define SCHUNK 1024
#define SNBLK ((NN + SCHUNK - 1) / SCHUNK)   // 98
#define FCH 25000                            // edges per fill chunk
#define FNC ((NE + FCH - 1) / FCH)           // 64 chunks

typedef __attribute__((ext_vector_type(8))) short bf16x8;
typedef __attribute__((ext_vector_type(8))) unsigned short u16x8;
typedef __attribute__((ext_vector_type(4))) float f32x4;

__device__ __forceinline__ float lrelu(float x) { return x > 0.f ? x : SLOPE * x; }
__device__ __forceinline__ ushort f2b(float f) {
    unsigned u = __float_as_uint(f);
    return (ushort)((u + 0x7FFFu + ((u >> 16) & 1u)) >> 16);  // RTNE fp32->bf16
}
__device__ __forceinline__ float b2f(ushort v) { return __uint_as_float(((unsigned)v) << 16); }

// ================= CSR build =================
__global__ void k_count(const int* __restrict__ dst, int* __restrict__ cnt) {
    int i = blockIdx.x * blockDim.x + threadIdx.x;
    if (i < NE) atomicAdd(&cnt[dst[i]], 1);
}

__global__ __launch_bounds__(256) void k_scan1(const int* __restrict__ cnt,
                                               int* __restrict__ rowptr,
                                               int* __restrict__ blksum) {
    __shared__ int ts[256];
    int base = blockIdx.x * SCHUNK + threadIdx.x * 4;
    int v0 = 0, v1 = 0, v2 = 0, v3 = 0;
    if (base < NN)     v0 = cnt[base];
    if (base + 1 < NN) v1 = cnt[base + 1];
    if (base + 2 < NN) v2 = cnt[base + 2];
    if (base + 3 < NN) v3 = cnt[base + 3];
    int s = v0 + v1 + v2 + v3;
    ts[threadIdx.x] = s;
    __syncthreads();
    for (int off = 1; off < 256; off <<= 1) {
        int w = (threadIdx.x >= off) ? ts[threadIdx.x - off] : 0;
        __syncthreads();
        ts[threadIdx.x] += w;
        __syncthreads();
    }
    int excl = ts[threadIdx.x] - s;
    if (base < NN)     rowptr[base]     = excl;
    if (base + 1 < NN) rowptr[base + 1] = excl + v0;
    if (base + 2 < NN) rowptr[base + 2] = excl + v0 + v1;
    if (base + 3 < NN) rowptr[base + 3] = excl + v0 + v1 + v2;
    if (threadIdx.x == 255) blksum[blockIdx.x] = ts[255];
}

__global__ __launch_bounds__(128) void k_scan2(int* __restrict__ blksum) {
    __shared__ int ts[128];
    int t = threadIdx.x;
    int v = (t < SNBLK) ? blksum[t] : 0;
    ts[t] = v;
    __syncthreads();
    for (int off = 1; off < 128; off <<= 1) {
        int w = (t >= off) ? ts[t - off] : 0;
        __syncthreads();
        ts[t] += w;
        __syncthreads();
    }
    if (t < SNBLK) blksum[t] = ts[t] - v;
}

__global__ void k_scan3(const int* __restrict__ blksum, const int* __restrict__ cnt,
                        int* __restrict__ rowptr, int* __restrict__ cursor,
                        float* __restrict__ invdeg) {
    int i = blockIdx.x * blockDim.x + threadIdx.x;
    if (i < NN) {
        int v = rowptr[i] + blksum[i >> 10];
        rowptr[i] = v;
        cursor[i] = v;
        invdeg[i] = 1.0f / fmaxf((float)cnt[i], 1.0f);
    }
    if (i == 0) rowptr[NN] = NE;
}

// XCD-partitioned fill: class (bid&7) handles dst range [xcd*12500, +12500);
// writes to each colsrc region come from one XCD class only -> L2 line merge.
__global__ __launch_bounds__(256) void k_fill_x(const int* __restrict__ src,
                                                const int* __restrict__ dst,
                                                int* __restrict__ cursor,
                                                int* __restrict__ colsrc) {
    int xcd = blockIdx.x & 7;
    int chunk = blockIdx.x >> 3;
    int lo = xcd * (NN / 8);
    int hi = (xcd == 7) ? NN : lo + (NN / 8);
    int beg = chunk * FCH;
    int end = min(beg + FCH, NE);
    for (int i = beg + (int)threadIdx.x; i < end; i += 256) {
        int d = dst[i];
        if (d >= lo && d < hi) {
            int pos = atomicAdd(&cursor[d], 1);
            colsrc[pos] = src[i];
        }
    }
}

// ================= fp32 tiled GEMM helpers (R12 form) =================
__device__ __forceinline__ void stageA(const float* __restrict__ g, int nbase, int ldg, int koff,
                                       float (*As)[AST]) {
    for (int i = threadIdx.x; i < 1024; i += 256) {
        int m = i >> 4, k4 = (i & 15) << 2;
        int row = nbase + m;
        if (row >= NN) row = NN - 1;
        *(float4*)&As[m][k4] = *(const float4*)&g[(size_t)row * ldg + koff + k4];
    }
}
__device__ __forceinline__ void stageW(const float* __restrict__ g, float* Ws) {
    for (int i = threadIdx.x; i < 1024; i += 256) ((float4*)Ws)[i] = ((const float4*)g)[i];
}
__device__ __forceinline__ void stageWcols(const float* __restrict__ g, int ldg, int coff,
                                           float* Ws) {
    for (int i = threadIdx.x; i < 1024; i += 256) {
        int r = i >> 4, c4 = (i & 15) << 2;
        *(float4*)&Ws[r * 64 + c4] = *(const float4*)&g[r * ldg + coff + c4];
    }
}
__device__ __forceinline__ void mac16v(const float (*As)[AST], const float* __restrict__ Ws,
                                       float (*acc)[4], int tr, int tc) {
#pragma unroll 4
    for (int k4 = 0; k4 < 64; k4 += 4) {
        float4 a0 = *(const float4*)&As[tr * 4 + 0][k4];
        float4 a1 = *(const float4*)&As[tr * 4 + 1][k4];
        float4 a2 = *(const float4*)&As[tr * 4 + 2][k4];
        float4 a3 = *(const float4*)&As[tr * 4 + 3][k4];
#pragma unroll
        for (int j = 0; j < 4; j++) {
            float4 w = *(const float4*)&Ws[(k4 + j) * 64 + tc * 4];
            float e0 = (&a0.x)[j], e1 = (&a1.x)[j], e2 = (&a2.x)[j], e3 = (&a3.x)[j];
            acc[0][0] += e0 * w.x; acc[0][1] += e0 * w.y; acc[0][2] += e0 * w.z; acc[0][3] += e0 * w.w;
            acc[1][0] += e1 * w.x; acc[1][1] += e1 * w.y; acc[1][2] += e1 * w.z; acc[1][3] += e1 * w.w;
            acc[2][0] += e2 * w.x; acc[2][1] += e2 * w.y; acc[2][2] += e2 * w.z; acc[2][3] += e2 * w.w;
            acc[3][0] += e3 * w.x; acc[3][1] += e3 * w.y; acc[3][2] += e3 * w.z; acc[3][3] += e3 * w.w;
        }
    }
}

// ================= n2v projection (fp32, R12 form) =================
__global__ __launch_bounds__(256) void k_n2vp_t(const float* __restrict__ n2v,
                                                const float* __restrict__ w,
                                                const float* __restrict__ b,
                                                float* __restrict__ n2vp) {
    __shared__ float As[64][AST];
    __shared__ float Ws[64 * 64];
    int nbase = blockIdx.x * 64;
    int tc = threadIdx.x & 15, tr = threadIdx.x >> 4;
    float acc[4][4] = {};
    for (int c = 0; c < 2; c++) {
        if (c) __syncthreads();
        stageA(n2v, nbase, EMBD, c * 64, As);
        stageW(w + c * 64 * 64, Ws);
        __syncthreads();
        mac16v(As, Ws, acc, tr, tc);
    }
    float b0 = b[tc * 4], b1 = b[tc * 4 + 1], b2 = b[tc * 4 + 2], b3 = b[tc * 4 + 3];
#pragma unroll
    for (int i = 0; i < 4; i++) {
        int row = nbase + tr * 4 + i;
        if (row < NN) {
            float4 o = {acc[i][0] + b0, acc[i][1] + b1, acc[i][2] + b2, acc[i][3] + b3};
            *(float4*)&n2vp[(size_t)row * HD + tc * 4] = o;
        }
    }
}

// ================= front: bf16 hi/lo split MFMA (R14) =================
__global__ __launch_bounds__(256) void k_front_t(const float* __restrict__ x,
                                                 const float* __restrict__ n2vp,
                                                 const float* __restrict__ ip_w,
                                                 const float* __restrict__ ip_b,
                                                 const float* __restrict__ gate_w,
                                                 const float* __restrict__ gate_b,
                                                 float* __restrict__ h0,
                                                 ushort* __restrict__ h0b) {
    __shared__ ushort Ah[64][40], Al[64][40];
    __shared__ ushort Bih[64][40], Bil[64][40];
    __shared__ ushort Bgh[64][40], Bgl[64][40];
    int nbase = blockIdx.x * 64;
    int tid = threadIdx.x;
    int w = tid >> 6, l = tid & 63;
    int lr = l & 15, lg = l >> 4, lk = lg * 8;
    f32x4 zero = {0.f, 0.f, 0.f, 0.f};
    f32x4 araw[4], ag[4], adel[4];
#pragma unroll
    for (int t = 0; t < 4; t++) { araw[t] = zero; ag[t] = zero; adel[t] = zero; }

    int arow = tid >> 2, ak0 = (tid & 3) << 3;
    int garow = nbase + arow;
    if (garow >= NN) garow = NN - 1;

    for (int c = 0; c < 8; c++) {
        if (c) __syncthreads();
        {
            const float* src = &x[(size_t)garow * DIN + c * 32 + ak0];
            u16x8 th, tl;
#pragma unroll
            for (int u = 0; u < 8; u++) {
                float v = src[u];
                ushort h = f2b(v);
                th[u] = h;
                tl[u] = f2b(v - b2f(h));
            }
            *(u16x8*)&Ah[arow][ak0] = th;
            *(u16x8*)&Al[arow][ak0] = tl;
        }
        {
            const float* pi = &ip_w[(size_t)(c * 32 + w * 8) * 64 + l];
            const float* pg = &gate_w[(size_t)(c * 32 + w * 8) * 64 + l];
            u16x8 ih, il, gh, gl2;
#pragma unroll
            for (int u = 0; u < 8; u++) {
                float v = pi[u * 64];
                ushort h = f2b(v);
                ih[u] = h; il[u] = f2b(v - b2f(h));
                float g = pg[u * 64];
                ushort hg = f2b(g);
                gh[u] = hg; gl2[u] = f2b(g - b2f(hg));
            }
            *(u16x8*)&Bih[l][w * 8] = ih;
            *(u16x8*)&Bil[l][w * 8] = il;
            *(u16x8*)&Bgh[l][w * 8] = gh;
            *(u16x8*)&Bgl[l][w * 8] = gl2;
        }
        __syncthreads();
        bf16x8 ah = *(const bf16x8*)&Ah[w * 16 + lr][lk];
        bf16x8 al = *(const bf16x8*)&Al[w * 16 + lr][lk];
#pragma unroll
        for (int t = 0; t < 4; t++) {
            int col = t * 16 + lr;
            bf16x8 bih = *(const bf16x8*)&Bih[col][lk];
            bf16x8 bil = *(const bf16x8*)&Bil[col][lk];
            bf16x8 bgh = *(const bf16x8*)&Bgh[col][lk];
            bf16x8 bgl = *(const bf16x8*)&Bgl[col][lk];
            f32x4 r = araw[t];
            r = __builtin_amdgcn_mfma_f32_16x16x32_bf16(ah, bih, r, 0, 0, 0);
            r = __builtin_amdgcn_mfma_f32_16x16x32_bf16(ah, bil, r, 0, 0, 0);
            r = __builtin_amdgcn_mfma_f32_16x16x32_bf16(al, bih, r, 0, 0, 0);
            araw[t] = r;
            f32x4 g = ag[t];
            g = __builtin_amdgcn_mfma_f32_16x16x32_bf16(ah, bgh, g, 0, 0, 0);
            g = __builtin_amdgcn_mfma_f32_16x16x32_bf16(ah, bgl, g, 0, 0, 0);
            g = __builtin_amdgcn_mfma_f32_16x16x32_bf16(al, bgh, g, 0, 0, 0);
            ag[t] = g;
        }
    }
    for (int c = 0; c < 2; c++) {
        __syncthreads();
        {
            const float* src = &n2vp[(size_t)garow * HD + c * 32 + ak0];
            u16x8 th, tl;
#pragma unroll
            for (int u = 0; u < 8; u++) {
                float v = src[u];
                ushort h = f2b(v);
                th[u] = h;
                tl[u] = f2b(v - b2f(h));
            }
            *(u16x8*)&Ah[arow][ak0] = th;
            *(u16x8*)&Al[arow][ak0] = tl;
        }
        {
            const float* pi = &ip_w[(size_t)(DIN + c * 32 + w * 8) * 64 + l];
            const float* pg = &gate_w[(size_t)(DIN + c * 32 + w * 8) * 64 + l];
            u16x8 ih, il, gh, gl2;
#pragma unroll
            for (int u = 0; u < 8; u++) {
                float v = pi[u * 64];
                ushort h = f2b(v);
                ih[u] = h; il[u] = f2b(v - b2f(h));
                float g = pg[u * 64];
                ushort hg = f2b(g);
                gh[u] = hg; gl2[u] = f2b(g - b2f(hg));
            }
            *(u16x8*)&Bih[l][w * 8] = ih;
            *(u16x8*)&Bil[l][w * 8] = il;
            *(u16x8*)&Bgh[l][w * 8] = gh;
            *(u16x8*)&Bgl[l][w * 8] = gl2;
        }
        __syncthreads();
        bf16x8 ah = *(const bf16x8*)&Ah[w * 16 + lr][lk];
        bf16x8 al = *(const bf16x8*)&Al[w * 16 + lr][lk];
#pragma unroll
        for (int t = 0; t < 4; t++) {
            int col = t * 16 + lr;
            bf16x8 bih = *(const bf16x8*)&Bih[col][lk];
            bf16x8 bil = *(const bf16x8*)&Bil[col][lk];
            bf16x8 bgh = *(const bf16x8*)&Bgh[col][lk];
            bf16x8 bgl = *(const bf16x8*)&Bgl[col][lk];
            f32x4 r = adel[t];
            r = __builtin_amdgcn_mfma_f32_16x16x32_bf16(ah, bih, r, 0, 0, 0);
            r = __builtin_amdgcn_mfma_f32_16x16x32_bf16(ah, bil, r, 0, 0, 0);
            r = __builtin_amdgcn_mfma_f32_16x16x32_bf16(al, bih, r, 0, 0, 0);
            adel[t] = r;
            f32x4 g = ag[t];
            g = __builtin_amdgcn_mfma_f32_16x16x32_bf16(ah, bgh, g, 0, 0, 0);
            g = __builtin_amdgcn_mfma_f32_16x16x32_bf16(ah, bgl, g, 0, 0, 0);
            g = __builtin_amdgcn_mfma_f32_16x16x32_bf16(al, bgh, g, 0, 0, 0);
            ag[t] = g;
        }
    }
#pragma unroll
    for (int t = 0; t < 4; t++) {
        int col = t * 16 + lr;
        float ib = ip_b[col], gb2 = gate_b[col];
#pragma unroll
        for (int r = 0; r < 4; r++) {
            int row = nbase + w * 16 + lg * 4 + r;
            if (row < NN) {
                float raw = araw[t][r] + ib;
                float sg = 1.f / (1.f + __expf(-(ag[t][r] + gb2)));
                float o = raw + sg * adel[t][r];
                h0[(size_t)row * HD + col] = o;
                h0b[(size_t)row * HD + col] = f2b(o);
            }
        }
    }
}

// ================= gather mean (R12) =================
__global__ void k_gather_mean(const int* __restrict__ rowptr, const int* __restrict__ colsrc,
                              const float* __restrict__ invdeg, const ushort* __restrict__ hb,
                              float* __restrict__ agg) {
    int t = threadIdx.x & 63;
    int lane = t & 31, half = t >> 5;
    int gw = blockIdx.x * (blockDim.x >> 6) + (threadIdx.x >> 6);
    int stride = gridDim.x * (blockDim.x >> 6);
    for (int n = gw; n < NN; n += stride) {
        int bg = rowptr[n], en = rowptr[n + 1];
        float a0 = 0.f, a1 = 0.f;
        int i = bg + half;
        for (; i + 6 < en; i += 8) {
            int sa = colsrc[i], sb = colsrc[i + 2], sc = colsrc[i + 4], sd = colsrc[i + 6];
            ushort2 va = *(const ushort2*)&hb[(size_t)sa * HD + lane * 2];
            ushort2 vb = *(const ushort2*)&hb[(size_t)sb * HD + lane * 2];
            ushort2 vc = *(const ushort2*)&hb[(size_t)sc * HD + lane * 2];
            ushort2 vd = *(const ushort2*)&hb[(size_t)sd * HD + lane * 2];
            a0 += b2f(va.x) + b2f(vb.x) + b2f(vc.x) + b2f(vd.x);
            a1 += b2f(va.y) + b2f(vb.y) + b2f(vc.y) + b2f(vd.y);
        }
        for (; i < en; i += 2) {
            int s = colsrc[i];
            ushort2 v = *(const ushort2*)&hb[(size_t)s * HD + lane * 2];
            a0 += b2f(v.x);
            a1 += b2f(v.y);
        }
        a0 += __shfl_xor(a0, 32);
        a1 += __shfl_xor(a1, 32);
        if (half == 0) {
            float id = invdeg[n];
            float2 o = {a0 * id, a1 * id};
            *(float2*)&agg[(size_t)n * HD + lane * 2] = o;
        }
    }
}

// ================= SAGE combine (R12) =================
__global__ __launch_bounds__(256) void k_sage_t(const float* __restrict__ agg,
                                                const float* __restrict__ h,
                                                const float* __restrict__ wl,
                                                const float* __restrict__ bl,
                                                const float* __restrict__ wr,
                                                float* __restrict__ hout,
                                                ushort* __restrict__ houtb) {
    __shared__ float As[64][AST];
    __shared__ float Ws[64 * 64];
    int nbase = blockIdx.x * 64;
    int tc = threadIdx.x & 15, tr = threadIdx.x >> 4;
    float acc[4][4] = {};
    stageA(agg, nbase, HD, 0, As);
    stageW(wl, Ws);
    __syncthreads();
    mac16v(As, Ws, acc, tr, tc);
    __syncthreads();
    stageA(h, nbase, HD, 0, As);
    stageW(wr, Ws);
    __syncthreads();
    mac16v(As, Ws, acc, tr, tc);
    float b0 = bl[tc * 4], b1 = bl[tc * 4 + 1], b2 = bl[tc * 4 + 2], b3 = bl[tc * 4 + 3];
#pragma unroll
    for (int i = 0; i < 4; i++) {
        int row = nbase + tr * 4 + i;
        if (row < NN) {
            float4 o = {fmaxf(acc[i][0] + b0, 0.f), fmaxf(acc[i][1] + b1, 0.f),
                        fmaxf(acc[i][2] + b2, 0.f), fmaxf(acc[i][3] + b3, 0.f)};
            *(float4*)&hout[(size_t)row * HD + tc * 4] = o;
            ushort4 ob = {f2b(o.x), f2b(o.y), f2b(o.z), f2b(o.w)};
            *(ushort4*)&houtb[(size_t)row * HD + tc * 4] = ob;
        }
    }
}

// ================= GAT transform (R12) =================
__global__ __launch_bounds__(256) void k_gatxh_t(const float* __restrict__ h,
                                                 const float* __restrict__ w,
                                                 const float* __restrict__ att_s,
                                                 const float* __restrict__ att_d,
                                                 ushort* __restrict__ xhb,
                                                 float* __restrict__ a_s,
                                                 float* __restrict__ a_d) {
    __shared__ float As[64][AST];
    __shared__ float Ws[64 * 64];
    int nbase = blockIdx.x * 64;
    int tc = threadIdx.x & 15, tr = threadIdx.x >> 4;
    stageA(h, nbase, HD, 0, As);
#pragma unroll
    for (int half = 0; half < 2; half++) {
        if (half) __syncthreads();
        stageWcols(w, 128, half * 64, Ws);
        __syncthreads();
        float acc[4][4] = {};
        mac16v(As, Ws, acc, tr, tc);
        float as0 = att_s[half * 64 + tc * 4], as1 = att_s[half * 64 + tc * 4 + 1];
        float as2 = att_s[half * 64 + tc * 4 + 2], as3 = att_s[half * 64 + tc * 4 + 3];
        float ad0 = att_d[half * 64 + tc * 4], ad1 = att_d[half * 64 + tc * 4 + 1];
        float ad2 = att_d[half * 64 + tc * 4 + 2], ad3 = att_d[half * 64 + tc * 4 + 3];
#pragma unroll
        for (int i = 0; i < 4; i++) {
            int row = nbase + tr * 4 + i;
            float ps = acc[i][0] * as0 + acc[i][1] * as1 + acc[i][2] * as2 + acc[i][3] * as3;
            float pd = acc[i][0] * ad0 + acc[i][1] * ad1 + acc[i][2] * ad2 + acc[i][3] * ad3;
#pragma unroll
            for (int off = 8; off; off >>= 1) {
                ps += __shfl_xor(ps, off);
                pd += __shfl_xor(pd, off);
            }
            if (row < NN) {
                ushort4 ob = {f2b(acc[i][0]), f2b(acc[i][1]), f2b(acc[i][2]), f2b(acc[i][3])};
                *(ushort4*)&xhb[(size_t)row * 128 + half * 64 + tc * 4] = ob;
                if (tc == 0) {
                    a_s[row * 2 + half] = ps;
                    a_d[row * 2 + half] = pd;
                }
            }
        }
    }
}

// ================= GAT fused (R12) =================
__global__ void k_gat_fused(const int* __restrict__ rowptr, const int* __restrict__ colsrc,
                            const float* __restrict__ a_s, const float* __restrict__ a_d,
                            const ushort* __restrict__ xhb, const float* __restrict__ gb,
                            float* __restrict__ hout) {
    int t = threadIdx.x & 63;
    int lane = t & 31, half = t >> 5;
    int bl4 = (lane & 15) * 4;
    float4 bias4 = *(const float4*)&gb[bl4];
    int gw = blockIdx.x * (blockDim.x >> 6) + (threadIdx.x >> 6);
    int stride = gridDim.x * (blockDim.x >> 6);
    for (int n = gw; n < NN; n += stride) {
        int bg = rowptr[n], en = rowptr[n + 1];
        float ad0 = a_d[n * 2], ad1 = a_d[n * 2 + 1];
        float a0 = 0.f, a1 = 0.f, a2 = 0.f, a3 = 0.f;
        float ss0 = 0.f, ss1 = 0.f;
        int i = bg + half;
        for (; i + 2 < en; i += 4) {
            int sa = colsrc[i], sb = colsrc[i + 2];
            float2 ava = *(const float2*)&a_s[sa * 2];
            float2 avb = *(const float2*)&a_s[sb * 2];
            ushort4 xva = *(const ushort4*)&xhb[(size_t)sa * 128 + lane * 4];
            ushort4 xvb = *(const ushort4*)&xhb[(size_t)sb * 128 + lane * 4];
            float wa0 = __expf(lrelu(ava.x + ad0));
            float wa1 = __expf(lrelu(ava.y + ad1));
            float wb0 = __expf(lrelu(avb.x + ad0));
            float wb1 = __expf(lrelu(avb.y + ad1));
            ss0 += wa0 + wb0;
            ss1 += wa1 + wb1;
            float wsa = (lane < 16) ? wa0 : wa1;
            float wsb = (lane < 16) ? wb0 : wb1;
            a0 += wsa * b2f(xva.x) + wsb * b2f(xvb.x);
            a1 += wsa * b2f(xva.y) + wsb * b2f(xvb.y);
            a2 += wsa * b2f(xva.z) + wsb * b2f(xvb.z);
            a3 += wsa * b2f(xva.w) + wsb * b2f(xvb.w);
        }
        for (; i < en; i += 2) {
            int s = colsrc[i];
            float2 av = *(const float2*)&a_s[s * 2];
            float w0 = __expf(lrelu(av.x + ad0));
            float w1 = __expf(lrelu(av.y + ad1));
            ss0 += w0;
            ss1 += w1;
            float wsel = (lane < 16) ? w0 : w1;
            ushort4 xv = *(const ushort4*)&xhb[(size_t)s * 128 + lane * 4];
            a0 += wsel * b2f(xv.x);
            a1 += wsel * b2f(xv.y);
            a2 += wsel * b2f(xv.z);
            a3 += wsel * b2f(xv.w);
        }
        if (half == 0) {  // self-loop
            float2 av = *(const float2*)&a_s[n * 2];
            float w0 = __expf(lrelu(av.x + ad0));
            float w1 = __expf(lrelu(av.y + ad1));
            ss0 += w0;
            ss1 += w1;
            float wsel = (lane < 16) ? w0 : w1;
            ushort4 xv = *(const ushort4*)&xhb[(size_t)n * 128 + lane * 4];
            a0 += wsel * b2f(xv.x);
            a1 += wsel * b2f(xv.y);
            a2 += wsel * b2f(xv.z);
            a3 += wsel * b2f(xv.w);
        }
        ss0 += __shfl_xor(ss0, 32);
        ss1 += __shfl_xor(ss1, 32);
        a0 += __shfl_xor(a0, 32);
        a1 += __shfl_xor(a1, 32);
        a2 += __shfl_xor(a2, 32);
        a3 += __shfl_xor(a3, 32);
        float r = (lane < 16) ? (0.5f / (ss0 + 1e-16f)) : (0.5f / (ss1 + 1e-16f));
        float v0 = a0 * r, v1 = a1 * r, v2 = a2 * r, v3 = a3 * r;
        float p0 = __shfl_xor(v0, 16);
        float p1 = __shfl_xor(v1, 16);
        float p2 = __shfl_xor(v2, 16);
        float p3 = __shfl_xor(v3, 16);
        if (half == 0 && lane < 16) {
            float4 o = {fmaxf(v0 + p0 + bias4.x, 0.f), fmaxf(v1 + p1 + bias4.y, 0.f),
                        fmaxf(v2 + p2 + bias4.z, 0.f), fmaxf(v3 + p3 + bias4.w, 0.f)};
            *(float4*)&hout[(size_t)n * HD + lane * 4] = o;
        }
    }
}

// ================= final SAGE (R12) =================
__global__ void k_pfin(const float* __restrict__ h, const float* __restrict__ wl,
                       ushort* __restrict__ Pb) {
    __shared__ float sw[HD * OUTD];
    for (int i = threadIdx.x; i < HD * OUTD; i += blockDim.x) sw[i] = wl[i];
    __syncthreads();
    int t = threadIdx.x & 63;
    int c = t & 31, half = t >> 5;
    int gw = blockIdx.x * (blockDim.x >> 6) + (threadIdx.x >> 6);
    int stride = gridDim.x * (blockDim.x >> 6);
    for (int n = gw; n < NN; n += stride) {
        float hv = h[(size_t)n * HD + t];
        float acc = 0.f;
#pragma unroll 8
        for (int i = 0; i < 32; i++) {
            float bb = __shfl(hv, half * 32 + i);
            acc += bb * sw[half * 1024 + i * 32 + c];
        }
        acc += __shfl_xor(acc, 32);
        if (half == 0) Pb[(size_t)n * OUTD + c] = f2b(acc);
    }
}

__global__ void k_final_fused(const int* __restrict__ rowptr, const int* __restrict__ colsrc,
                              const float* __restrict__ invdeg, const ushort* __restrict__ Pb,
                              const float* __restrict__ h, const float* __restrict__ bl,
                              const float* __restrict__ wr, float* __restrict__ out) {
    __shared__ float sw[HD * OUTD];
    for (int i = threadIdx.x; i < HD * OUTD; i += blockDim.x) sw[i] = wr[i];
    __syncthreads();
    int t = threadIdx.x & 63;
    int j = t & 31, half = t >> 5;
    int quarter = t >> 4, lane16 = t & 15;
    float bias = bl[j];
    int gw = blockIdx.x * (blockDim.x >> 6) + (threadIdx.x >> 6);
    int stride = gridDim.x * (blockDim.x >> 6);
    for (int n = gw; n < NN; n += stride) {
        int bg = rowptr[n], en = rowptr[n + 1];
        float a0 = 0.f, a1 = 0.f;
        int i = bg + quarter;
        for (; i + 4 < en; i += 8) {
            int sa = colsrc[i], sb = colsrc[i + 4];
            ushort2 va = *(const ushort2*)&Pb[(size_t)sa * OUTD + lane16 * 2];
            ushort2 vb = *(const ushort2*)&Pb[(size_t)sb * OUTD + lane16 * 2];
            a0 += b2f(va.x) + b2f(vb.x);
            a1 += b2f(va.y) + b2f(vb.y);
        }
        for (; i < en; i += 4) {
            int s = colsrc[i];
            ushort2 v = *(const ushort2*)&Pb[(size_t)s * OUTD + lane16 * 2];
            a0 += b2f(v.x);
            a1 += b2f(v.y);
        }
        a0 += __shfl_xor(a0, 32);
        a1 += __shfl_xor(a1, 32);
        a0 += __shfl_xor(a0, 16);
        a1 += __shfl_xor(a1, 16);
        float hv = h[(size_t)n * HD + t];
        float o = 0.f;
#pragma unroll 8
        for (int i2 = 0; i2 < 32; i2++) {
            float bb = __shfl(hv, half * 32 + i2);
            o += bb * sw[half * 1024 + i2 * 32 + j];
        }
        o += __shfl_xor(o, 32);
        float ga = __shfl(a0, j >> 1);
        float gb_ = __shfl(a1, j >> 1);
        float gv = (j & 1) ? gb_ : ga;
        if (half == 0) out[(size_t)n * OUTD + j] = gv * invdeg[n] + bias + o;
    }
}

// ================= launch =================
extern "C" void kernel_launch(void* const* d_in, const int* in_sizes, int n_in,
                              void* d_out, int out_size, void* d_ws, size_t ws_size,
                              hipStream_t stream) {
    const float* x      = (const float*)d_in[0];
    const int*   eidx   = (const int*)d_in[1];
    const float* n2v    = (const float*)d_in[2];
    const float* n2v_w  = (const float*)d_in[3];
    const float* n2v_b  = (const float*)d_in[4];
    const float* ip_w   = (const float*)d_in[5];
    const float* ip_b   = (const float*)d_in[6];
    const float* gate_w = (const float*)d_in[7];
    const float* gate_b = (const float*)d_in[8];
    const float* s0_wl  = (const float*)d_in[9];
    const float* s0_bl  = (const float*)d_in[10];
    const float* s0_wr  = (const float*)d_in[11];
    const float* s1_wl  = (const float*)d_in[12];
    const float* s1_bl  = (const float*)d_in[13];
    const float* s1_wr  = (const float*)d_in[14];
    const float* gat_w  = (const float*)d_in[15];
    const float* att_s  = (const float*)d_in[16];
    const float* att_d  = (const float*)d_in[17];
    const float* gat_b  = (const float*)d_in[18];
    const float* f_wl   = (const float*)d_in[19];
    const float* f_bl   = (const float*)d_in[20];
    const float* f_wr   = (const float*)d_in[21];

    const int* src = eidx;
    const int* dst = eidx + NE;

    // ---- workspace ----
    float*  ws     = (float*)d_ws;
    float*  invdeg = ws;                         // N
    float*  S1     = invdeg + NN;                // 64N  (h1, h3)
    float*  S2     = S1 + (size_t)NN * HD;       // 64N  (h0, h2)
    float*  SA     = S2 + (size_t)NN * HD;       // 64N  (n2vp / agg)
    float*  a_s    = SA + (size_t)NN * HD;       // 2N
    float*  a_d    = a_s + (size_t)NN * 2;       // 2N
    ushort* Pb     = (ushort*)(a_d + (size_t)NN * 2);   // 32N ushort
    ushort* hb     = Pb + (size_t)NN * OUTD;            // 64N ushort
    ushort* xhb    = hb + (size_t)NN * HD;              // 128N ushort
    int*    cnt    = (int*)(xhb + (size_t)NN * 128);    // N
    int*    rowptr = cnt + NN;                   // N+1
    int*    cursor = rowptr + NN + 1;            // N
    int*    blksum = cursor + NN;                // 128
    int*    colsrc = blksum + 128;               // NE

    float* n2vp = SA;
    float* agg  = SA;
    float* out  = (float*)d_out;

    const int BT = 256;
    dim3 b128(128), b256(BT);
    int eblk = (NE + BT - 1) / BT;
    int nblk = (NN + BT - 1) / BT;

    // ---- CSR ----
    hipMemsetAsync(cnt, 0, (size_t)NN * 4, stream);
    k_count<<<eblk, b256, 0, stream>>>(dst, cnt);
    k_scan1<<<SNBLK, b256, 0, stream>>>(cnt, rowptr, blksum);
    k_scan2<<<1, b128, 0, stream>>>(blksum);
    k_scan3<<<nblk, b256, 0, stream>>>(blksum, cnt, rowptr, cursor, invdeg);
    k_fill_x<<<8 * FNC, b256, 0, stream>>>(src, dst, cursor, colsrc);

    // ---- front ----
    k_n2vp_t<<<NT, b256, 0, stream>>>(n2v, n2v_w, n2v_b, n2vp);
    k_front_t<<<NT, b256, 0, stream>>>(x, n2vp, ip_w, ip_b, gate_w, gate_b, S2, hb);

    // ---- SAGE 0: S2 -> S1 ----
    k_gather_mean<<<2048, b256, 0, stream>>>(rowptr, colsrc, invdeg, hb, agg);
    k_sage_t<<<NT, b256, 0, stream>>>(agg, S2, s0_wl, s0_bl, s0_wr, S1, hb);

    // ---- SAGE 1: S1 -> S2 ----
    k_gather_mean<<<2048, b256, 0, stream>>>(rowptr, colsrc, invdeg, hb, agg);
    k_sage_t<<<NT, b256, 0, stream>>>(agg, S1, s1_wl, s1_bl, s1_wr, S2, hb);

    // ---- GAT: S2 -> S1 ----
    k_gatxh_t<<<NT, b256, 0, stream>>>(S2, gat_w, att_s, att_d, xhb, a_s, a_d);
    k_gat_fused<<<2048, b256, 0, stream>>>(rowptr, colsrc, a_s, a_d, xhb, gat_b, S1);

    // ---- final SAGE: S1 -> out ----
    k_pfin<<<2048, b256, 0, stream>>>(S1, f_wl, Pb);
    k_final_fused<<<2048, b256, 0, stream>>>(rowptr, colsrc, invdeg, Pb, S1, f_bl, f_wr, out);
}

// Round 17
// 670.859 us; speedup vs baseline: 1.2499x; 1.0370x over previous
//
#include <hip/hip_runtime.h>
#include <math.h>

#define NN 100000
#define NE 1600000
#define DIN 256
#define HD 64
#define OUTD 32
#define EMBD 128
#define SLOPE 0.2f
#define AST 68
#define NT ((NN + 63) / 64)
#define SCHUNK 1024
#define SNBLK ((NN + SCHUNK - 1) / SCHUNK)   // 98
#define FCH 25000
#define FNC ((NE + FCH - 1) / FCH)           // 64 chunks

typedef __attribute__((ext_vector_type(8))) short bf16x8;
typedef __attribute__((ext_vector_type(8))) unsigned short u16x8;
typedef __attribute__((ext_vector_type(4))) float f32x4;

__device__ __forceinline__ float lrelu(float x) { return x > 0.f ? x : SLOPE * x; }
__device__ __forceinline__ ushort f2b(float f) {
    unsigned u = __float_as_uint(f);
    return (ushort)((u + 0x7FFFu + ((u >> 16) & 1u)) >> 16);  // RTNE fp32->bf16
}
__device__ __forceinline__ float b2f(ushort v) { return __uint_as_float(((unsigned)v) << 16); }

// ================= CSR build =================
__global__ void k_count(const int* __restrict__ dst, int* __restrict__ cnt) {
    int i = blockIdx.x * blockDim.x + threadIdx.x;
    if (i < NE) atomicAdd(&cnt[dst[i]], 1);
}

__global__ __launch_bounds__(256) void k_scan1(const int* __restrict__ cnt,
                                               int* __restrict__ rowptr,
                                               int* __restrict__ blksum) {
    __shared__ int ts[256];
    int base = blockIdx.x * SCHUNK + threadIdx.x * 4;
    int v0 = 0, v1 = 0, v2 = 0, v3 = 0;
    if (base < NN)     v0 = cnt[base];
    if (base + 1 < NN) v1 = cnt[base + 1];
    if (base + 2 < NN) v2 = cnt[base + 2];
    if (base + 3 < NN) v3 = cnt[base + 3];
    int s = v0 + v1 + v2 + v3;
    ts[threadIdx.x] = s;
    __syncthreads();
    for (int off = 1; off < 256; off <<= 1) {
        int w = (threadIdx.x >= off) ? ts[threadIdx.x - off] : 0;
        __syncthreads();
        ts[threadIdx.x] += w;
        __syncthreads();
    }
    int excl = ts[threadIdx.x] - s;
    if (base < NN)     rowptr[base]     = excl;
    if (base + 1 < NN) rowptr[base + 1] = excl + v0;
    if (base + 2 < NN) rowptr[base + 2] = excl + v0 + v1;
    if (base + 3 < NN) rowptr[base + 3] = excl + v0 + v1 + v2;
    if (threadIdx.x == 255) blksum[blockIdx.x] = ts[255];
}

__global__ __launch_bounds__(128) void k_scan2(int* __restrict__ blksum) {
    __shared__ int ts[128];
    int t = threadIdx.x;
    int v = (t < SNBLK) ? blksum[t] : 0;
    ts[t] = v;
    __syncthreads();
    for (int off = 1; off < 128; off <<= 1) {
        int w = (t >= off) ? ts[t - off] : 0;
        __syncthreads();
        ts[t] += w;
        __syncthreads();
    }
    if (t < SNBLK) blksum[t] = ts[t] - v;
}

__global__ void k_scan3(const int* __restrict__ blksum, const int* __restrict__ cnt,
                        int* __restrict__ rowptr, int* __restrict__ cursor,
                        float* __restrict__ invdeg) {
    int i = blockIdx.x * blockDim.x + threadIdx.x;
    if (i < NN) {
        int v = rowptr[i] + blksum[i >> 10];
        rowptr[i] = v;
        cursor[i] = v;
        invdeg[i] = 1.0f / fmaxf((float)cnt[i], 1.0f);
    }
    if (i == 0) rowptr[NN] = NE;
}

// ================= fp32 tiled GEMM helpers (R12 form) =================
__device__ __forceinline__ void stageA(const float* __restrict__ g, int nbase, int ldg, int koff,
                                       float (*As)[AST]) {
    for (int i = threadIdx.x; i < 1024; i += 256) {
        int m = i >> 4, k4 = (i & 15) << 2;
        int row = nbase + m;
        if (row >= NN) row = NN - 1;
        *(float4*)&As[m][k4] = *(const float4*)&g[(size_t)row * ldg + koff + k4];
    }
}
__device__ __forceinline__ void stageW(const float* __restrict__ g, float* Ws) {
    for (int i = threadIdx.x; i < 1024; i += 256) ((float4*)Ws)[i] = ((const float4*)g)[i];
}
__device__ __forceinline__ void stageWcols(const float* __restrict__ g, int ldg, int coff,
                                           float* Ws) {
    for (int i = threadIdx.x; i < 1024; i += 256) {
        int r = i >> 4, c4 = (i & 15) << 2;
        *(float4*)&Ws[r * 64 + c4] = *(const float4*)&g[r * ldg + coff + c4];
    }
}
__device__ __forceinline__ void mac16v(const float (*As)[AST], const float* __restrict__ Ws,
                                       float (*acc)[4], int tr, int tc) {
#pragma unroll 4
    for (int k4 = 0; k4 < 64; k4 += 4) {
        float4 a0 = *(const float4*)&As[tr * 4 + 0][k4];
        float4 a1 = *(const float4*)&As[tr * 4 + 1][k4];
        float4 a2 = *(const float4*)&As[tr * 4 + 2][k4];
        float4 a3 = *(const float4*)&As[tr * 4 + 3][k4];
#pragma unroll
        for (int j = 0; j < 4; j++) {
            float4 w = *(const float4*)&Ws[(k4 + j) * 64 + tc * 4];
            float e0 = (&a0.x)[j], e1 = (&a1.x)[j], e2 = (&a2.x)[j], e3 = (&a3.x)[j];
            acc[0][0] += e0 * w.x; acc[0][1] += e0 * w.y; acc[0][2] += e0 * w.z; acc[0][3] += e0 * w.w;
            acc[1][0] += e1 * w.x; acc[1][1] += e1 * w.y; acc[1][2] += e1 * w.z; acc[1][3] += e1 * w.w;
            acc[2][0] += e2 * w.x; acc[2][1] += e2 * w.y; acc[2][2] += e2 * w.z; acc[2][3] += e2 * w.w;
            acc[3][0] += e3 * w.x; acc[3][1] += e3 * w.y; acc[3][2] += e3 * w.z; acc[3][3] += e3 * w.w;
        }
    }
}

// ================= mega-front: CSR fill blocks + MFMA front blocks =================
__global__ __launch_bounds__(256) void k_megafront(
        const float* __restrict__ x, const float* __restrict__ n2v,
        const float* __restrict__ n2v_w, const float* __restrict__ n2v_b,
        const float* __restrict__ ip_w, const float* __restrict__ ip_b,
        const float* __restrict__ gate_w, const float* __restrict__ gate_b,
        float* __restrict__ h0, ushort* __restrict__ h0b,
        const int* __restrict__ esrc, const int* __restrict__ edst,
        int* __restrict__ cursor, int* __restrict__ colsrc) {
    __shared__ ushort Ah[64][40], Al[64][40];
    __shared__ ushort Bih[64][40], Bil[64][40];
    __shared__ ushort Bgh[64][40], Bgl[64][40];

    if (blockIdx.x >= NT) {
        // ---------- fill path (XCD-partitioned) ----------
        int fb = blockIdx.x - NT;
        int cls = blockIdx.x & 7;      // constant per actual XCD (heuristic)
        int chunk = fb >> 3;
        int lo = cls * (NN / 8);
        int hi = (cls == 7) ? NN : lo + (NN / 8);
        int beg = chunk * FCH;
        int end = min(beg + FCH, NE);
        for (int i = beg + (int)threadIdx.x; i < end; i += 256) {
            int d = edst[i];
            if (d >= lo && d < hi) {
                int pos = atomicAdd(&cursor[d], 1);
                colsrc[pos] = esrc[i];
            }
        }
        return;
    }

    // ---------- front path (n2vp fused in, split-bf16 MFMA) ----------
    int nbase = blockIdx.x * 64;
    int tid = threadIdx.x;
    int w = tid >> 6, l = tid & 63;
    int lr = l & 15, lg = l >> 4, lk = lg * 8;
    f32x4 zero = {0.f, 0.f, 0.f, 0.f};
    f32x4 araw[4], ag[4], adel[4], pn[4];
#pragma unroll
    for (int t = 0; t < 4; t++) { araw[t] = zero; ag[t] = zero; adel[t] = zero; pn[t] = zero; }

    int arow = tid >> 2, ak0 = (tid & 3) << 3;
    int garow = nbase + arow;
    if (garow >= NN) garow = NN - 1;

    // --- phase 0: n2vp = n2v @ n2v_w (K=128, 4 chunks) ---
    for (int c = 0; c < 4; c++) {
        if (c) __syncthreads();
        {
            const float* ap = &n2v[(size_t)garow * EMBD + c * 32 + ak0];
            u16x8 th, tl;
#pragma unroll
            for (int u = 0; u < 8; u++) {
                float v = ap[u];
                ushort h = f2b(v);
                th[u] = h;
                tl[u] = f2b(v - b2f(h));
            }
            *(u16x8*)&Ah[arow][ak0] = th;
            *(u16x8*)&Al[arow][ak0] = tl;
        }
        {
            const float* pw = &n2v_w[(size_t)(c * 32 + w * 8) * 64 + l];
            u16x8 ih, il;
#pragma unroll
            for (int u = 0; u < 8; u++) {
                float v = pw[u * 64];
                ushort h = f2b(v);
                ih[u] = h;
                il[u] = f2b(v - b2f(h));
            }
            *(u16x8*)&Bih[l][w * 8] = ih;
            *(u16x8*)&Bil[l][w * 8] = il;
        }
        __syncthreads();
        bf16x8 ah = *(const bf16x8*)&Ah[w * 16 + lr][lk];
        bf16x8 al = *(const bf16x8*)&Al[w * 16 + lr][lk];
#pragma unroll
        for (int t = 0; t < 4; t++) {
            int col = t * 16 + lr;
            bf16x8 bih = *(const bf16x8*)&Bih[col][lk];
            bf16x8 bil = *(const bf16x8*)&Bil[col][lk];
            f32x4 r = pn[t];
            r = __builtin_amdgcn_mfma_f32_16x16x32_bf16(ah, bih, r, 0, 0, 0);
            r = __builtin_amdgcn_mfma_f32_16x16x32_bf16(ah, bil, r, 0, 0, 0);
            r = __builtin_amdgcn_mfma_f32_16x16x32_bf16(al, bih, r, 0, 0, 0);
            pn[t] = r;
        }
    }
    // add n2v bias
#pragma unroll
    for (int t = 0; t < 4; t++) {
        float nb = n2v_b[t * 16 + lr];
#pragma unroll
        for (int r = 0; r < 4; r++) pn[t][r] += nb;
    }

    // --- phase 1: 8 chunks of x -> araw, ag ---
    for (int c = 0; c < 8; c++) {
        __syncthreads();
        {
            const float* ap = &x[(size_t)garow * DIN + c * 32 + ak0];
            u16x8 th, tl;
#pragma unroll
            for (int u = 0; u < 8; u++) {
                float v = ap[u];
                ushort h = f2b(v);
                th[u] = h;
                tl[u] = f2b(v - b2f(h));
            }
            *(u16x8*)&Ah[arow][ak0] = th;
            *(u16x8*)&Al[arow][ak0] = tl;
        }
        {
            const float* pi = &ip_w[(size_t)(c * 32 + w * 8) * 64 + l];
            const float* pg = &gate_w[(size_t)(c * 32 + w * 8) * 64 + l];
            u16x8 ih, il, gh, gl2;
#pragma unroll
            for (int u = 0; u < 8; u++) {
                float v = pi[u * 64];
                ushort h = f2b(v);
                ih[u] = h; il[u] = f2b(v - b2f(h));
                float g = pg[u * 64];
                ushort hg = f2b(g);
                gh[u] = hg; gl2[u] = f2b(g - b2f(hg));
            }
            *(u16x8*)&Bih[l][w * 8] = ih;
            *(u16x8*)&Bil[l][w * 8] = il;
            *(u16x8*)&Bgh[l][w * 8] = gh;
            *(u16x8*)&Bgl[l][w * 8] = gl2;
        }
        __syncthreads();
        bf16x8 ah = *(const bf16x8*)&Ah[w * 16 + lr][lk];
        bf16x8 al = *(const bf16x8*)&Al[w * 16 + lr][lk];
#pragma unroll
        for (int t = 0; t < 4; t++) {
            int col = t * 16 + lr;
            bf16x8 bih = *(const bf16x8*)&Bih[col][lk];
            bf16x8 bil = *(const bf16x8*)&Bil[col][lk];
            bf16x8 bgh = *(const bf16x8*)&Bgh[col][lk];
            bf16x8 bgl = *(const bf16x8*)&Bgl[col][lk];
            f32x4 r = araw[t];
            r = __builtin_amdgcn_mfma_f32_16x16x32_bf16(ah, bih, r, 0, 0, 0);
            r = __builtin_amdgcn_mfma_f32_16x16x32_bf16(ah, bil, r, 0, 0, 0);
            r = __builtin_amdgcn_mfma_f32_16x16x32_bf16(al, bih, r, 0, 0, 0);
            araw[t] = r;
            f32x4 g = ag[t];
            g = __builtin_amdgcn_mfma_f32_16x16x32_bf16(ah, bgh, g, 0, 0, 0);
            g = __builtin_amdgcn_mfma_f32_16x16x32_bf16(ah, bgl, g, 0, 0, 0);
            g = __builtin_amdgcn_mfma_f32_16x16x32_bf16(al, bgh, g, 0, 0, 0);
            ag[t] = g;
        }
    }

    // --- phase 2: 2 tail chunks from in-register pn -> adel, ag ---
    for (int c = 0; c < 2; c++) {
        __syncthreads();
        // write pn half (cols c*32 .. c*32+31) into Ah/Al
#pragma unroll
        for (int tt = 0; tt < 2; tt++) {
            int t = c * 2 + tt;
            int ak = tt * 16 + lr;   // col within chunk
#pragma unroll
            for (int r = 0; r < 4; r++) {
                int row = w * 16 + lg * 4 + r;
                float v = pn[t][r];
                ushort h = f2b(v);
                Ah[row][ak] = h;
                Al[row][ak] = f2b(v - b2f(h));
            }
        }
        {
            const float* pi = &ip_w[(size_t)(DIN + c * 32 + w * 8) * 64 + l];
            const float* pg = &gate_w[(size_t)(DIN + c * 32 + w * 8) * 64 + l];
            u16x8 ih, il, gh, gl2;
#pragma unroll
            for (int u = 0; u < 8; u++) {
                float v = pi[u * 64];
                ushort h = f2b(v);
                ih[u] = h; il[u] = f2b(v - b2f(h));
                float g = pg[u * 64];
                ushort hg = f2b(g);
                gh[u] = hg; gl2[u] = f2b(g - b2f(hg));
            }
            *(u16x8*)&Bih[l][w * 8] = ih;
            *(u16x8*)&Bil[l][w * 8] = il;
            *(u16x8*)&Bgh[l][w * 8] = gh;
            *(u16x8*)&Bgl[l][w * 8] = gl2;
        }
        __syncthreads();
        bf16x8 ah = *(const bf16x8*)&Ah[w * 16 + lr][lk];
        bf16x8 al = *(const bf16x8*)&Al[w * 16 + lr][lk];
#pragma unroll
        for (int t = 0; t < 4; t++) {
            int col = t * 16 + lr;
            bf16x8 bih = *(const bf16x8*)&Bih[col][lk];
            bf16x8 bil = *(const bf16x8*)&Bil[col][lk];
            bf16x8 bgh = *(const bf16x8*)&Bgh[col][lk];
            bf16x8 bgl = *(const bf16x8*)&Bgl[col][lk];
            f32x4 r = adel[t];
            r = __builtin_amdgcn_mfma_f32_16x16x32_bf16(ah, bih, r, 0, 0, 0);
            r = __builtin_amdgcn_mfma_f32_16x16x32_bf16(ah, bil, r, 0, 0, 0);
            r = __builtin_amdgcn_mfma_f32_16x16x32_bf16(al, bih, r, 0, 0, 0);
            adel[t] = r;
            f32x4 g = ag[t];
            g = __builtin_amdgcn_mfma_f32_16x16x32_bf16(ah, bgh, g, 0, 0, 0);
            g = __builtin_amdgcn_mfma_f32_16x16x32_bf16(ah, bgl, g, 0, 0, 0);
            g = __builtin_amdgcn_mfma_f32_16x16x32_bf16(al, bgh, g, 0, 0, 0);
            ag[t] = g;
        }
    }
    // --- epilogue ---
#pragma unroll
    for (int t = 0; t < 4; t++) {
        int col = t * 16 + lr;
        float ib = ip_b[col], gb2 = gate_b[col];
#pragma unroll
        for (int r = 0; r < 4; r++) {
            int row = nbase + w * 16 + lg * 4 + r;
            if (row < NN) {
                float raw = araw[t][r] + ib;
                float sg = 1.f / (1.f + __expf(-(ag[t][r] + gb2)));
                float o = raw + sg * adel[t][r];
                h0[(size_t)row * HD + col] = o;
                h0b[(size_t)row * HD + col] = f2b(o);
            }
        }
    }
}

// ================= gather mean (R12) =================
__global__ void k_gather_mean(const int* __restrict__ rowptr, const int* __restrict__ colsrc,
                              const float* __restrict__ invdeg, const ushort* __restrict__ hb,
                              float* __restrict__ agg) {
    int t = threadIdx.x & 63;
    int lane = t & 31, half = t >> 5;
    int gw = blockIdx.x * (blockDim.x >> 6) + (threadIdx.x >> 6);
    int stride = gridDim.x * (blockDim.x >> 6);
    for (int n = gw; n < NN; n += stride) {
        int bg = rowptr[n], en = rowptr[n + 1];
        float a0 = 0.f, a1 = 0.f;
        int i = bg + half;
        for (; i + 6 < en; i += 8) {
            int sa = colsrc[i], sb = colsrc[i + 2], sc = colsrc[i + 4], sd = colsrc[i + 6];
            ushort2 va = *(const ushort2*)&hb[(size_t)sa * HD + lane * 2];
            ushort2 vb = *(const ushort2*)&hb[(size_t)sb * HD + lane * 2];
            ushort2 vc = *(const ushort2*)&hb[(size_t)sc * HD + lane * 2];
            ushort2 vd = *(const ushort2*)&hb[(size_t)sd * HD + lane * 2];
            a0 += b2f(va.x) + b2f(vb.x) + b2f(vc.x) + b2f(vd.x);
            a1 += b2f(va.y) + b2f(vb.y) + b2f(vc.y) + b2f(vd.y);
        }
        for (; i < en; i += 2) {
            int s = colsrc[i];
            ushort2 v = *(const ushort2*)&hb[(size_t)s * HD + lane * 2];
            a0 += b2f(v.x);
            a1 += b2f(v.y);
        }
        a0 += __shfl_xor(a0, 32);
        a1 += __shfl_xor(a1, 32);
        if (half == 0) {
            float id = invdeg[n];
            float2 o = {a0 * id, a1 * id};
            *(float2*)&agg[(size_t)n * HD + lane * 2] = o;
        }
    }
}

// ================= SAGE combine (R12) =================
__global__ __launch_bounds__(256) void k_sage_t(const float* __restrict__ agg,
                                                const float* __restrict__ h,
                                                const float* __restrict__ wl,
                                                const float* __restrict__ bl,
                                                const float* __restrict__ wr,
                                                float* __restrict__ hout,
                                                ushort* __restrict__ houtb) {
    __shared__ float As[64][AST];
    __shared__ float Ws[64 * 64];
    int nbase = blockIdx.x * 64;
    int tc = threadIdx.x & 15, tr = threadIdx.x >> 4;
    float acc[4][4] = {};
    stageA(agg, nbase, HD, 0, As);
    stageW(wl, Ws);
    __syncthreads();
    mac16v(As, Ws, acc, tr, tc);
    __syncthreads();
    stageA(h, nbase, HD, 0, As);
    stageW(wr, Ws);
    __syncthreads();
    mac16v(As, Ws, acc, tr, tc);
    float b0 = bl[tc * 4], b1 = bl[tc * 4 + 1], b2 = bl[tc * 4 + 2], b3 = bl[tc * 4 + 3];
#pragma unroll
    for (int i = 0; i < 4; i++) {
        int row = nbase + tr * 4 + i;
        if (row < NN) {
            float4 o = {fmaxf(acc[i][0] + b0, 0.f), fmaxf(acc[i][1] + b1, 0.f),
                        fmaxf(acc[i][2] + b2, 0.f), fmaxf(acc[i][3] + b3, 0.f)};
            *(float4*)&hout[(size_t)row * HD + tc * 4] = o;
            ushort4 ob = {f2b(o.x), f2b(o.y), f2b(o.z), f2b(o.w)};
            *(ushort4*)&houtb[(size_t)row * HD + tc * 4] = ob;
        }
    }
}

// ================= GAT transform (R12) =================
__global__ __launch_bounds__(256) void k_gatxh_t(const float* __restrict__ h,
                                                 const float* __restrict__ w,
                                                 const float* __restrict__ att_s,
                                                 const float* __restrict__ att_d,
                                                 ushort* __restrict__ xhb,
                                                 float* __restrict__ a_s,
                                                 float* __restrict__ a_d) {
    __shared__ float As[64][AST];
    __shared__ float Ws[64 * 64];
    int nbase = blockIdx.x * 64;
    int tc = threadIdx.x & 15, tr = threadIdx.x >> 4;
    stageA(h, nbase, HD, 0, As);
#pragma unroll
    for (int half = 0; half < 2; half++) {
        if (half) __syncthreads();
        stageWcols(w, 128, half * 64, Ws);
        __syncthreads();
        float acc[4][4] = {};
        mac16v(As, Ws, acc, tr, tc);
        float as0 = att_s[half * 64 + tc * 4], as1 = att_s[half * 64 + tc * 4 + 1];
        float as2 = att_s[half * 64 + tc * 4 + 2], as3 = att_s[half * 64 + tc * 4 + 3];
        float ad0 = att_d[half * 64 + tc * 4], ad1 = att_d[half * 64 + tc * 4 + 1];
        float ad2 = att_d[half * 64 + tc * 4 + 2], ad3 = att_d[half * 64 + tc * 4 + 3];
#pragma unroll
        for (int i = 0; i < 4; i++) {
            int row = nbase + tr * 4 + i;
            float ps = acc[i][0] * as0 + acc[i][1] * as1 + acc[i][2] * as2 + acc[i][3] * as3;
            float pd = acc[i][0] * ad0 + acc[i][1] * ad1 + acc[i][2] * ad2 + acc[i][3] * ad3;
#pragma unroll
            for (int off = 8; off; off >>= 1) {
                ps += __shfl_xor(ps, off);
                pd += __shfl_xor(pd, off);
            }
            if (row < NN) {
                ushort4 ob = {f2b(acc[i][0]), f2b(acc[i][1]), f2b(acc[i][2]), f2b(acc[i][3])};
                *(ushort4*)&xhb[(size_t)row * 128 + half * 64 + tc * 4] = ob;
                if (tc == 0) {
                    a_s[row * 2 + half] = ps;
                    a_d[row * 2 + half] = pd;
                }
            }
        }
    }
}

// ================= GAT fused (R12) =================
__global__ void k_gat_fused(const int* __restrict__ rowptr, const int* __restrict__ colsrc,
                            const float* __restrict__ a_s, const float* __restrict__ a_d,
                            const ushort* __restrict__ xhb, const float* __restrict__ gb,
                            float* __restrict__ hout) {
    int t = threadIdx.x & 63;
    int lane = t & 31, half = t >> 5;
    int bl4 = (lane & 15) * 4;
    float4 bias4 = *(const float4*)&gb[bl4];
    int gw = blockIdx.x * (blockDim.x >> 6) + (threadIdx.x >> 6);
    int stride = gridDim.x * (blockDim.x >> 6);
    for (int n = gw; n < NN; n += stride) {
        int bg = rowptr[n], en = rowptr[n + 1];
        float ad0 = a_d[n * 2], ad1 = a_d[n * 2 + 1];
        float a0 = 0.f, a1 = 0.f, a2 = 0.f, a3 = 0.f;
        float ss0 = 0.f, ss1 = 0.f;
        int i = bg + half;
        for (; i + 2 < en; i += 4) {
            int sa = colsrc[i], sb = colsrc[i + 2];
            float2 ava = *(const float2*)&a_s[sa * 2];
            float2 avb = *(const float2*)&a_s[sb * 2];
            ushort4 xva = *(const ushort4*)&xhb[(size_t)sa * 128 + lane * 4];
            ushort4 xvb = *(const ushort4*)&xhb[(size_t)sb * 128 + lane * 4];
            float wa0 = __expf(lrelu(ava.x + ad0));
            float wa1 = __expf(lrelu(ava.y + ad1));
            float wb0 = __expf(lrelu(avb.x + ad0));
            float wb1 = __expf(lrelu(avb.y + ad1));
            ss0 += wa0 + wb0;
            ss1 += wa1 + wb1;
            float wsa = (lane < 16) ? wa0 : wa1;
            float wsb = (lane < 16) ? wb0 : wb1;
            a0 += wsa * b2f(xva.x) + wsb * b2f(xvb.x);
            a1 += wsa * b2f(xva.y) + wsb * b2f(xvb.y);
            a2 += wsa * b2f(xva.z) + wsb * b2f(xvb.z);
            a3 += wsa * b2f(xva.w) + wsb * b2f(xvb.w);
        }
        for (; i < en; i += 2) {
            int s = colsrc[i];
            float2 av = *(const float2*)&a_s[s * 2];
            float w0 = __expf(lrelu(av.x + ad0));
            float w1 = __expf(lrelu(av.y + ad1));
            ss0 += w0;
            ss1 += w1;
            float wsel = (lane < 16) ? w0 : w1;
            ushort4 xv = *(const ushort4*)&xhb[(size_t)s * 128 + lane * 4];
            a0 += wsel * b2f(xv.x);
            a1 += wsel * b2f(xv.y);
            a2 += wsel * b2f(xv.z);
            a3 += wsel * b2f(xv.w);
        }
        if (half == 0) {  // self-loop
            float2 av = *(const float2*)&a_s[n * 2];
            float w0 = __expf(lrelu(av.x + ad0));
            float w1 = __expf(lrelu(av.y + ad1));
            ss0 += w0;
            ss1 += w1;
            float wsel = (lane < 16) ? w0 : w1;
            ushort4 xv = *(const ushort4*)&xhb[(size_t)n * 128 + lane * 4];
            a0 += wsel * b2f(xv.x);
            a1 += wsel * b2f(xv.y);
            a2 += wsel * b2f(xv.z);
            a3 += wsel * b2f(xv.w);
        }
        ss0 += __shfl_xor(ss0, 32);
        ss1 += __shfl_xor(ss1, 32);
        a0 += __shfl_xor(a0, 32);
        a1 += __shfl_xor(a1, 32);
        a2 += __shfl_xor(a2, 32);
        a3 += __shfl_xor(a3, 32);
        float r = (lane < 16) ? (0.5f / (ss0 + 1e-16f)) : (0.5f / (ss1 + 1e-16f));
        float v0 = a0 * r, v1 = a1 * r, v2 = a2 * r, v3 = a3 * r;
        float p0 = __shfl_xor(v0, 16);
        float p1 = __shfl_xor(v1, 16);
        float p2 = __shfl_xor(v2, 16);
        float p3 = __shfl_xor(v3, 16);
        if (half == 0 && lane < 16) {
            float4 o = {fmaxf(v0 + p0 + bias4.x, 0.f), fmaxf(v1 + p1 + bias4.y, 0.f),
                        fmaxf(v2 + p2 + bias4.z, 0.f), fmaxf(v3 + p3 + bias4.w, 0.f)};
            *(float4*)&hout[(size_t)n * HD + lane * 4] = o;
        }
    }
}

// ================= final SAGE (R12) =================
__global__ void k_pfin(const float* __restrict__ h, const float* __restrict__ wl,
                       ushort* __restrict__ Pb) {
    __shared__ float sw[HD * OUTD];
    for (int i = threadIdx.x; i < HD * OUTD; i += blockDim.x) sw[i] = wl[i];
    __syncthreads();
    int t = threadIdx.x & 63;
    int c = t & 31, half = t >> 5;
    int gw = blockIdx.x * (blockDim.x >> 6) + (threadIdx.x >> 6);
    int stride = gridDim.x * (blockDim.x >> 6);
    for (int n = gw; n < NN; n += stride) {
        float hv = h[(size_t)n * HD + t];
        float acc = 0.f;
#pragma unroll 8
        for (int i = 0; i < 32; i++) {
            float bb = __shfl(hv, half * 32 + i);
            acc += bb * sw[half * 1024 + i * 32 + c];
        }
        acc += __shfl_xor(acc, 32);
        if (half == 0) Pb[(size_t)n * OUTD + c] = f2b(acc);
    }
}

__global__ void k_final_fused(const int* __restrict__ rowptr, const int* __restrict__ colsrc,
                              const float* __restrict__ invdeg, const ushort* __restrict__ Pb,
                              const float* __restrict__ h, const float* __restrict__ bl,
                              const float* __restrict__ wr, float* __restrict__ out) {
    __shared__ float sw[HD * OUTD];
    for (int i = threadIdx.x; i < HD * OUTD; i += blockDim.x) sw[i] = wr[i];
    __syncthreads();
    int t = threadIdx.x & 63;
    int j = t & 31, half = t >> 5;
    int quarter = t >> 4, lane16 = t & 15;
    float bias = bl[j];
    int gw = blockIdx.x * (blockDim.x >> 6) + (threadIdx.x >> 6);
    int stride = gridDim.x * (blockDim.x >> 6);
    for (int n = gw; n < NN; n += stride) {
        int bg = rowptr[n], en = rowptr[n + 1];
        float a0 = 0.f, a1 = 0.f;
        int i = bg + quarter;
        for (; i + 4 < en; i += 8) {
            int sa = colsrc[i], sb = colsrc[i + 4];
            ushort2 va = *(const ushort2*)&Pb[(size_t)sa * OUTD + lane16 * 2];
            ushort2 vb = *(const ushort2*)&Pb[(size_t)sb * OUTD + lane16 * 2];
            a0 += b2f(va.x) + b2f(vb.x);
            a1 += b2f(va.y) + b2f(vb.y);
        }
        for (; i < en; i += 4) {
            int s = colsrc[i];
            ushort2 v = *(const ushort2*)&Pb[(size_t)s * OUTD + lane16 * 2];
            a0 += b2f(v.x);
            a1 += b2f(v.y);
        }
        a0 += __shfl_xor(a0, 32);
        a1 += __shfl_xor(a1, 32);
        a0 += __shfl_xor(a0, 16);
        a1 += __shfl_xor(a1, 16);
        float hv = h[(size_t)n * HD + t];
        float o = 0.f;
#pragma unroll 8
        for (int i2 = 0; i2 < 32; i2++) {
            float bb = __shfl(hv, half * 32 + i2);
            o += bb * sw[half * 1024 + i2 * 32 + j];
        }
        o += __shfl_xor(o, 32);
        float ga = __shfl(a0, j >> 1);
        float gb_ = __shfl(a1, j >> 1);
        float gv = (j & 1) ? gb_ : ga;
        if (half == 0) out[(size_t)n * OUTD + j] = gv * invdeg[n] + bias + o;
    }
}

// ================= launch =================
extern "C" void kernel_launch(void* const* d_in, const int* in_sizes, int n_in,
                              void* d_out, int out_size, void* d_ws, size_t ws_size,
                              hipStream_t stream) {
    const float* x      = (const float*)d_in[0];
    const int*   eidx   = (const int*)d_in[1];
    const float* n2v    = (const float*)d_in[2];
    const float* n2v_w  = (const float*)d_in[3];
    const float* n2v_b  = (const float*)d_in[4];
    const float* ip_w   = (const float*)d_in[5];
    const float* ip_b   = (const float*)d_in[6];
    const float* gate_w = (const float*)d_in[7];
    const float* gate_b = (const float*)d_in[8];
    const float* s0_wl  = (const float*)d_in[9];
    const float* s0_bl  = (const float*)d_in[10];
    const float* s0_wr  = (const float*)d_in[11];
    const float* s1_wl  = (const float*)d_in[12];
    const float* s1_bl  = (const float*)d_in[13];
    const float* s1_wr  = (const float*)d_in[14];
    const float* gat_w  = (const float*)d_in[15];
    const float* att_s  = (const float*)d_in[16];
    const float* att_d  = (const float*)d_in[17];
    const float* gat_b  = (const float*)d_in[18];
    const float* f_wl   = (const float*)d_in[19];
    const float* f_bl   = (const float*)d_in[20];
    const float* f_wr   = (const float*)d_in[21];

    const int* src = eidx;
    const int* dst = eidx + NE;

    // ---- workspace ----
    float*  ws     = (float*)d_ws;
    float*  invdeg = ws;                         // N
    float*  S1     = invdeg + NN;                // 64N  (h1, h3)
    float*  S2     = S1 + (size_t)NN * HD;       // 64N  (h0, h2)
    float*  SA     = S2 + (size_t)NN * HD;       // 64N  (agg)
    float*  a_s    = SA + (size_t)NN * HD;       // 2N
    float*  a_d    = a_s + (size_t)NN * 2;       // 2N
    ushort* Pb     = (ushort*)(a_d + (size_t)NN * 2);   // 32N ushort
    ushort* hb     = Pb + (size_t)NN * OUTD;            // 64N ushort
    ushort* xhb    = hb + (size_t)NN * HD;              // 128N ushort
    int*    cnt    = (int*)(xhb + (size_t)NN * 128);    // N
    int*    rowptr = cnt + NN;                   // N+1
    int*    cursor = rowptr + NN + 1;            // N
    int*    blksum = cursor + NN;                // 128
    int*    colsrc = blksum + 128;               // NE

    float* agg = SA;
    float* out = (float*)d_out;

    const int BT = 256;
    dim3 b128(128), b256(BT);
    int eblk = (NE + BT - 1) / BT;
    int nblk = (NN + BT - 1) / BT;

    // ---- CSR prefix ----
    hipMemsetAsync(cnt, 0, (size_t)NN * 4, stream);
    k_count<<<eblk, b256, 0, stream>>>(dst, cnt);
    k_scan1<<<SNBLK, b256, 0, stream>>>(cnt, rowptr, blksum);
    k_scan2<<<1, b128, 0, stream>>>(blksum);
    k_scan3<<<nblk, b256, 0, stream>>>(blksum, cnt, rowptr, cursor, invdeg);

    // ---- mega: CSR fill + front (overlapped) ----
    k_megafront<<<NT + 8 * FNC, b256, 0, stream>>>(x, n2v, n2v_w, n2v_b, ip_w, ip_b,
                                                   gate_w, gate_b, S2, hb,
                                                   src, dst, cursor, colsrc);

    // ---- SAGE 0: S2 -> S1 ----
    k_gather_mean<<<2048, b256, 0, stream>>>(rowptr, colsrc, invdeg, hb, agg);
    k_sage_t<<<NT, b256, 0, stream>>>(agg, S2, s0_wl, s0_bl, s0_wr, S1, hb);

    // ---- SAGE 1: S1 -> S2 ----
    k_gather_mean<<<2048, b256, 0, stream>>>(rowptr, colsrc, invdeg, hb, agg);
    k_sage_t<<<NT, b256, 0, stream>>>(agg, S1, s1_wl, s1_bl, s1_wr, S2, hb);

    // ---- GAT: S2 -> S1 ----
    k_gatxh_t<<<NT, b256, 0, stream>>>(S2, gat_w, att_s, att_d, xhb, a_s, a_d);
    k_gat_fused<<<2048, b256, 0, stream>>>(rowptr, colsrc, a_s, a_d, xhb, gat_b, S1);

    // ---- final SAGE: S1 -> out ----
    k_pfin<<<2048, b256, 0, stream>>>(S1, f_wl, Pb);
    k_final_fused<<<2048, b256, 0, stream>>>(rowptr, colsrc, invdeg, Pb, S1, f_bl, f_wr, out);
}

// Round 18
// 662.336 us; speedup vs baseline: 1.2660x; 1.0129x over previous
//
#include <hip/hip_runtime.h>
#include <math.h>

#define NN 100000
#define NE 1600000
#define DIN 256
#define HD 64
#define OUTD 32
#define EMBD 128
#define SLOPE 0.2f
#define AST 68
#define NT ((NN + 63) / 64)
#define SCHUNK 1024
#define SNBLK ((NN + SCHUNK - 1) / SCHUNK)   // 98
#define FCH 25000
#define FNC ((NE + FCH - 1) / FCH)           // 64 chunks
#define NFILL (8 * FNC)                      // 512 fill blocks (scheduled FIRST)

typedef __attribute__((ext_vector_type(8))) short bf16x8;
typedef __attribute__((ext_vector_type(8))) unsigned short u16x8;
typedef __attribute__((ext_vector_type(4))) float f32x4;

__device__ __forceinline__ float lrelu(float x) { return x > 0.f ? x : SLOPE * x; }
__device__ __forceinline__ ushort f2b(float f) {
    unsigned u = __float_as_uint(f);
    return (ushort)((u + 0x7FFFu + ((u >> 16) & 1u)) >> 16);  // RTNE fp32->bf16
}
__device__ __forceinline__ float b2f(ushort v) { return __uint_as_float(((unsigned)v) << 16); }

// ================= CSR build =================
__global__ void k_count(const int* __restrict__ dst, int* __restrict__ cnt) {
    int i = blockIdx.x * blockDim.x + threadIdx.x;
    if (i < NE) atomicAdd(&cnt[dst[i]], 1);
}

__global__ __launch_bounds__(256) void k_scan1(const int* __restrict__ cnt,
                                               int* __restrict__ rowptr,
                                               int* __restrict__ blksum) {
    __shared__ int ts[256];
    int base = blockIdx.x * SCHUNK + threadIdx.x * 4;
    int v0 = 0, v1 = 0, v2 = 0, v3 = 0;
    if (base < NN)     v0 = cnt[base];
    if (base + 1 < NN) v1 = cnt[base + 1];
    if (base + 2 < NN) v2 = cnt[base + 2];
    if (base + 3 < NN) v3 = cnt[base + 3];
    int s = v0 + v1 + v2 + v3;
    ts[threadIdx.x] = s;
    __syncthreads();
    for (int off = 1; off < 256; off <<= 1) {
        int w = (threadIdx.x >= off) ? ts[threadIdx.x - off] : 0;
        __syncthreads();
        ts[threadIdx.x] += w;
        __syncthreads();
    }
    int excl = ts[threadIdx.x] - s;
    if (base < NN)     rowptr[base]     = excl;
    if (base + 1 < NN) rowptr[base + 1] = excl + v0;
    if (base + 2 < NN) rowptr[base + 2] = excl + v0 + v1;
    if (base + 3 < NN) rowptr[base + 3] = excl + v0 + v1 + v2;
    if (threadIdx.x == 255) blksum[blockIdx.x] = ts[255];
}

__global__ __launch_bounds__(128) void k_scan2(int* __restrict__ blksum) {
    __shared__ int ts[128];
    int t = threadIdx.x;
    int v = (t < SNBLK) ? blksum[t] : 0;
    ts[t] = v;
    __syncthreads();
    for (int off = 1; off < 128; off <<= 1) {
        int w = (t >= off) ? ts[t - off] : 0;
        __syncthreads();
        ts[t] += w;
        __syncthreads();
    }
    if (t < SNBLK) blksum[t] = ts[t] - v;
}

__global__ void k_scan3(const int* __restrict__ blksum, const int* __restrict__ cnt,
                        int* __restrict__ rowptr, int* __restrict__ cursor,
                        float* __restrict__ invdeg) {
    int i = blockIdx.x * blockDim.x + threadIdx.x;
    if (i < NN) {
        int v = rowptr[i] + blksum[i >> 10];
        rowptr[i] = v;
        cursor[i] = v;
        invdeg[i] = 1.0f / fmaxf((float)cnt[i], 1.0f);
    }
    if (i == 0) rowptr[NN] = NE;
}

// ================= fp32 tiled GEMM helpers =================
__device__ __forceinline__ void stageA(const float* __restrict__ g, int nbase, int ldg, int koff,
                                       float (*As)[AST]) {
    for (int i = threadIdx.x; i < 1024; i += 256) {
        int m = i >> 4, k4 = (i & 15) << 2;
        int row = nbase + m;
        if (row >= NN) row = NN - 1;
        *(float4*)&As[m][k4] = *(const float4*)&g[(size_t)row * ldg + koff + k4];
    }
}
// bf16 source variant (converts on stage)
__device__ __forceinline__ void stageAb(const ushort* __restrict__ g, int nbase, int ldg,
                                        float (*As)[AST]) {
    for (int i = threadIdx.x; i < 1024; i += 256) {
        int m = i >> 4, k4 = (i & 15) << 2;
        int row = nbase + m;
        if (row >= NN) row = NN - 1;
        ushort4 v = *(const ushort4*)&g[(size_t)row * ldg + k4];
        As[m][k4] = b2f(v.x); As[m][k4 + 1] = b2f(v.y);
        As[m][k4 + 2] = b2f(v.z); As[m][k4 + 3] = b2f(v.w);
    }
}
__device__ __forceinline__ void stageW(const float* __restrict__ g, float* Ws) {
    for (int i = threadIdx.x; i < 1024; i += 256) ((float4*)Ws)[i] = ((const float4*)g)[i];
}
__device__ __forceinline__ void stageWcols(const float* __restrict__ g, int ldg, int coff,
                                           float* Ws) {
    for (int i = threadIdx.x; i < 1024; i += 256) {
        int r = i >> 4, c4 = (i & 15) << 2;
        *(float4*)&Ws[r * 64 + c4] = *(const float4*)&g[r * ldg + coff + c4];
    }
}
__device__ __forceinline__ void mac16v(const float (*As)[AST], const float* __restrict__ Ws,
                                       float (*acc)[4], int tr, int tc) {
#pragma unroll 4
    for (int k4 = 0; k4 < 64; k4 += 4) {
        float4 a0 = *(const float4*)&As[tr * 4 + 0][k4];
        float4 a1 = *(const float4*)&As[tr * 4 + 1][k4];
        float4 a2 = *(const float4*)&As[tr * 4 + 2][k4];
        float4 a3 = *(const float4*)&As[tr * 4 + 3][k4];
#pragma unroll
        for (int j = 0; j < 4; j++) {
            float4 w = *(const float4*)&Ws[(k4 + j) * 64 + tc * 4];
            float e0 = (&a0.x)[j], e1 = (&a1.x)[j], e2 = (&a2.x)[j], e3 = (&a3.x)[j];
            acc[0][0] += e0 * w.x; acc[0][1] += e0 * w.y; acc[0][2] += e0 * w.z; acc[0][3] += e0 * w.w;
            acc[1][0] += e1 * w.x; acc[1][1] += e1 * w.y; acc[1][2] += e1 * w.z; acc[1][3] += e1 * w.w;
            acc[2][0] += e2 * w.x; acc[2][1] += e2 * w.y; acc[2][2] += e2 * w.z; acc[2][3] += e2 * w.w;
            acc[3][0] += e3 * w.x; acc[3][1] += e3 * w.y; acc[3][2] += e3 * w.z; acc[3][3] += e3 * w.w;
        }
    }
}

// ================= mega-front: fill blocks FIRST, then MFMA front blocks =================
__global__ __launch_bounds__(256) void k_megafront(
        const float* __restrict__ x, const float* __restrict__ n2v,
        const float* __restrict__ n2v_w, const float* __restrict__ n2v_b,
        const float* __restrict__ ip_w, const float* __restrict__ ip_b,
        const float* __restrict__ gate_w, const float* __restrict__ gate_b,
        float* __restrict__ h0, ushort* __restrict__ h0b,
        const int* __restrict__ esrc, const int* __restrict__ edst,
        int* __restrict__ cursor, int* __restrict__ colsrc) {
    __shared__ ushort Ah[64][40], Al[64][40];
    __shared__ ushort Bih[64][40], Bil[64][40];
    __shared__ ushort Bgh[64][40], Bgl[64][40];

    if (blockIdx.x < NFILL) {
        // ---------- fill path (XCD-partitioned, scheduled first) ----------
        int cls = blockIdx.x & 7;
        int chunk = blockIdx.x >> 3;
        int lo = cls * (NN / 8);
        int hi = (cls == 7) ? NN : lo + (NN / 8);
        int beg = chunk * FCH;
        int end = min(beg + FCH, NE);
        for (int i = beg + (int)threadIdx.x; i < end; i += 256) {
            int d = edst[i];
            if (d >= lo && d < hi) {
                int pos = atomicAdd(&cursor[d], 1);
                colsrc[pos] = esrc[i];
            }
        }
        return;
    }

    // ---------- front path ----------
    int nbase = (blockIdx.x - NFILL) * 64;
    int tid = threadIdx.x;
    int w = tid >> 6, l = tid & 63;
    int lr = l & 15, lg = l >> 4, lk = lg * 8;
    f32x4 zero = {0.f, 0.f, 0.f, 0.f};
    f32x4 araw[4], ag[4], adel[4], pn[4];
#pragma unroll
    for (int t = 0; t < 4; t++) { araw[t] = zero; ag[t] = zero; adel[t] = zero; pn[t] = zero; }

    int arow = tid >> 2, ak0 = (tid & 3) << 3;
    int garow = nbase + arow;
    if (garow >= NN) garow = NN - 1;

    // --- phase 0: n2vp = n2v @ n2v_w (K=128, 4 chunks) ---
    for (int c = 0; c < 4; c++) {
        if (c) __syncthreads();
        {
            const float* ap = &n2v[(size_t)garow * EMBD + c * 32 + ak0];
            u16x8 th, tl;
#pragma unroll
            for (int u = 0; u < 8; u++) {
                float v = ap[u];
                ushort h = f2b(v);
                th[u] = h;
                tl[u] = f2b(v - b2f(h));
            }
            *(u16x8*)&Ah[arow][ak0] = th;
            *(u16x8*)&Al[arow][ak0] = tl;
        }
        {
            const float* pw = &n2v_w[(size_t)(c * 32 + w * 8) * 64 + l];
            u16x8 ih, il;
#pragma unroll
            for (int u = 0; u < 8; u++) {
                float v = pw[u * 64];
                ushort h = f2b(v);
                ih[u] = h;
                il[u] = f2b(v - b2f(h));
            }
            *(u16x8*)&Bih[l][w * 8] = ih;
            *(u16x8*)&Bil[l][w * 8] = il;
        }
        __syncthreads();
        bf16x8 ah = *(const bf16x8*)&Ah[w * 16 + lr][lk];
        bf16x8 al = *(const bf16x8*)&Al[w * 16 + lr][lk];
#pragma unroll
        for (int t = 0; t < 4; t++) {
            int col = t * 16 + lr;
            bf16x8 bih = *(const bf16x8*)&Bih[col][lk];
            bf16x8 bil = *(const bf16x8*)&Bil[col][lk];
            f32x4 r = pn[t];
            r = __builtin_amdgcn_mfma_f32_16x16x32_bf16(ah, bih, r, 0, 0, 0);
            r = __builtin_amdgcn_mfma_f32_16x16x32_bf16(ah, bil, r, 0, 0, 0);
            r = __builtin_amdgcn_mfma_f32_16x16x32_bf16(al, bih, r, 0, 0, 0);
            pn[t] = r;
        }
    }
#pragma unroll
    for (int t = 0; t < 4; t++) {
        float nb = n2v_b[t * 16 + lr];
#pragma unroll
        for (int r = 0; r < 4; r++) pn[t][r] += nb;
    }

    // --- phase 1: 8 chunks of x -> araw, ag ---
    for (int c = 0; c < 8; c++) {
        __syncthreads();
        {
            const float* ap = &x[(size_t)garow * DIN + c * 32 + ak0];
            u16x8 th, tl;
#pragma unroll
            for (int u = 0; u < 8; u++) {
                float v = ap[u];
                ushort h = f2b(v);
                th[u] = h;
                tl[u] = f2b(v - b2f(h));
            }
            *(u16x8*)&Ah[arow][ak0] = th;
            *(u16x8*)&Al[arow][ak0] = tl;
        }
        {
            const float* pi = &ip_w[(size_t)(c * 32 + w * 8) * 64 + l];
            const float* pg = &gate_w[(size_t)(c * 32 + w * 8) * 64 + l];
            u16x8 ih, il, gh, gl2;
#pragma unroll
            for (int u = 0; u < 8; u++) {
                float v = pi[u * 64];
                ushort h = f2b(v);
                ih[u] = h; il[u] = f2b(v - b2f(h));
                float g = pg[u * 64];
                ushort hg = f2b(g);
                gh[u] = hg; gl2[u] = f2b(g - b2f(hg));
            }
            *(u16x8*)&Bih[l][w * 8] = ih;
            *(u16x8*)&Bil[l][w * 8] = il;
            *(u16x8*)&Bgh[l][w * 8] = gh;
            *(u16x8*)&Bgl[l][w * 8] = gl2;
        }
        __syncthreads();
        bf16x8 ah = *(const bf16x8*)&Ah[w * 16 + lr][lk];
        bf16x8 al = *(const bf16x8*)&Al[w * 16 + lr][lk];
#pragma unroll
        for (int t = 0; t < 4; t++) {
            int col = t * 16 + lr;
            bf16x8 bih = *(const bf16x8*)&Bih[col][lk];
            bf16x8 bil = *(const bf16x8*)&Bil[col][lk];
            bf16x8 bgh = *(const bf16x8*)&Bgh[col][lk];
            bf16x8 bgl = *(const bf16x8*)&Bgl[col][lk];
            f32x4 r = araw[t];
            r = __builtin_amdgcn_mfma_f32_16x16x32_bf16(ah, bih, r, 0, 0, 0);
            r = __builtin_amdgcn_mfma_f32_16x16x32_bf16(ah, bil, r, 0, 0, 0);
            r = __builtin_amdgcn_mfma_f32_16x16x32_bf16(al, bih, r, 0, 0, 0);
            araw[t] = r;
            f32x4 g = ag[t];
            g = __builtin_amdgcn_mfma_f32_16x16x32_bf16(ah, bgh, g, 0, 0, 0);
            g = __builtin_amdgcn_mfma_f32_16x16x32_bf16(ah, bgl, g, 0, 0, 0);
            g = __builtin_amdgcn_mfma_f32_16x16x32_bf16(al, bgh, g, 0, 0, 0);
            ag[t] = g;
        }
    }

    // --- phase 2: 2 tail chunks from in-register pn -> adel, ag ---
    for (int c = 0; c < 2; c++) {
        __syncthreads();
#pragma unroll
        for (int tt = 0; tt < 2; tt++) {
            int t = c * 2 + tt;
            int ak = tt * 16 + lr;
#pragma unroll
            for (int r = 0; r < 4; r++) {
                int row = w * 16 + lg * 4 + r;
                float v = pn[t][r];
                ushort h = f2b(v);
                Ah[row][ak] = h;
                Al[row][ak] = f2b(v - b2f(h));
            }
        }
        {
            const float* pi = &ip_w[(size_t)(DIN + c * 32 + w * 8) * 64 + l];
            const float* pg = &gate_w[(size_t)(DIN + c * 32 + w * 8) * 64 + l];
            u16x8 ih, il, gh, gl2;
#pragma unroll
            for (int u = 0; u < 8; u++) {
                float v = pi[u * 64];
                ushort h = f2b(v);
                ih[u] = h; il[u] = f2b(v - b2f(h));
                float g = pg[u * 64];
                ushort hg = f2b(g);
                gh[u] = hg; gl2[u] = f2b(g - b2f(hg));
            }
            *(u16x8*)&Bih[l][w * 8] = ih;
            *(u16x8*)&Bil[l][w * 8] = il;
            *(u16x8*)&Bgh[l][w * 8] = gh;
            *(u16x8*)&Bgl[l][w * 8] = gl2;
        }
        __syncthreads();
        bf16x8 ah = *(const bf16x8*)&Ah[w * 16 + lr][lk];
        bf16x8 al = *(const bf16x8*)&Al[w * 16 + lr][lk];
#pragma unroll
        for (int t = 0; t < 4; t++) {
            int col = t * 16 + lr;
            bf16x8 bih = *(const bf16x8*)&Bih[col][lk];
            bf16x8 bil = *(const bf16x8*)&Bil[col][lk];
            bf16x8 bgh = *(const bf16x8*)&Bgh[col][lk];
            bf16x8 bgl = *(const bf16x8*)&Bgl[col][lk];
            f32x4 r = adel[t];
            r = __builtin_amdgcn_mfma_f32_16x16x32_bf16(ah, bih, r, 0, 0, 0);
            r = __builtin_amdgcn_mfma_f32_16x16x32_bf16(ah, bil, r, 0, 0, 0);
            r = __builtin_amdgcn_mfma_f32_16x16x32_bf16(al, bih, r, 0, 0, 0);
            adel[t] = r;
            f32x4 g = ag[t];
            g = __builtin_amdgcn_mfma_f32_16x16x32_bf16(ah, bgh, g, 0, 0, 0);
            g = __builtin_amdgcn_mfma_f32_16x16x32_bf16(ah, bgl, g, 0, 0, 0);
            g = __builtin_amdgcn_mfma_f32_16x16x32_bf16(al, bgh, g, 0, 0, 0);
            ag[t] = g;
        }
    }
    // --- epilogue ---
#pragma unroll
    for (int t = 0; t < 4; t++) {
        int col = t * 16 + lr;
        float ib = ip_b[col], gb2 = gate_b[col];
#pragma unroll
        for (int r = 0; r < 4; r++) {
            int row = nbase + w * 16 + lg * 4 + r;
            if (row < NN) {
                float raw = araw[t][r] + ib;
                float sg = 1.f / (1.f + __expf(-(ag[t][r] + gb2)));
                float o = raw + sg * adel[t][r];
                h0[(size_t)row * HD + col] = o;
                h0b[(size_t)row * HD + col] = f2b(o);
            }
        }
    }
}

// ================= gather mean (writes bf16 agg) =================
__global__ void k_gather_mean(const int* __restrict__ rowptr, const int* __restrict__ colsrc,
                              const float* __restrict__ invdeg, const ushort* __restrict__ hb,
                              ushort* __restrict__ aggb) {
    int t = threadIdx.x & 63;
    int lane = t & 31, half = t >> 5;
    int gw = blockIdx.x * (blockDim.x >> 6) + (threadIdx.x >> 6);
    int stride = gridDim.x * (blockDim.x >> 6);
    for (int n = gw; n < NN; n += stride) {
        int bg = rowptr[n], en = rowptr[n + 1];
        float a0 = 0.f, a1 = 0.f;
        int i = bg + half;
        for (; i + 6 < en; i += 8) {
            int sa = colsrc[i], sb = colsrc[i + 2], sc = colsrc[i + 4], sd = colsrc[i + 6];
            ushort2 va = *(const ushort2*)&hb[(size_t)sa * HD + lane * 2];
            ushort2 vb = *(const ushort2*)&hb[(size_t)sb * HD + lane * 2];
            ushort2 vc = *(const ushort2*)&hb[(size_t)sc * HD + lane * 2];
            ushort2 vd = *(const ushort2*)&hb[(size_t)sd * HD + lane * 2];
            a0 += b2f(va.x) + b2f(vb.x) + b2f(vc.x) + b2f(vd.x);
            a1 += b2f(va.y) + b2f(vb.y) + b2f(vc.y) + b2f(vd.y);
        }
        for (; i < en; i += 2) {
            int s = colsrc[i];
            ushort2 v = *(const ushort2*)&hb[(size_t)s * HD + lane * 2];
            a0 += b2f(v.x);
            a1 += b2f(v.y);
        }
        a0 += __shfl_xor(a0, 32);
        a1 += __shfl_xor(a1, 32);
        if (half == 0) {
            float id = invdeg[n];
            ushort2 o = {f2b(a0 * id), f2b(a1 * id)};
            *(ushort2*)&aggb[(size_t)n * HD + lane * 2] = o;
        }
    }
}

// ================= SAGE combine (bf16 agg in) =================
__global__ __launch_bounds__(256) void k_sage_t(const ushort* __restrict__ aggb,
                                                const float* __restrict__ h,
                                                const float* __restrict__ wl,
                                                const float* __restrict__ bl,
                                                const float* __restrict__ wr,
                                                float* __restrict__ hout,
                                                ushort* __restrict__ houtb) {
    __shared__ float As[64][AST];
    __shared__ float Ws[64 * 64];
    int nbase = blockIdx.x * 64;
    int tc = threadIdx.x & 15, tr = threadIdx.x >> 4;
    float acc[4][4] = {};
    stageAb(aggb, nbase, HD, As);
    stageW(wl, Ws);
    __syncthreads();
    mac16v(As, Ws, acc, tr, tc);
    __syncthreads();
    stageA(h, nbase, HD, 0, As);
    stageW(wr, Ws);
    __syncthreads();
    mac16v(As, Ws, acc, tr, tc);
    float b0 = bl[tc * 4], b1 = bl[tc * 4 + 1], b2 = bl[tc * 4 + 2], b3 = bl[tc * 4 + 3];
#pragma unroll
    for (int i = 0; i < 4; i++) {
        int row = nbase + tr * 4 + i;
        if (row < NN) {
            float4 o = {fmaxf(acc[i][0] + b0, 0.f), fmaxf(acc[i][1] + b1, 0.f),
                        fmaxf(acc[i][2] + b2, 0.f), fmaxf(acc[i][3] + b3, 0.f)};
            *(float4*)&hout[(size_t)row * HD + tc * 4] = o;
            ushort4 ob = {f2b(o.x), f2b(o.y), f2b(o.z), f2b(o.w)};
            *(ushort4*)&houtb[(size_t)row * HD + tc * 4] = ob;
        }
    }
}

// ================= GAT transform (R12) =================
__global__ __launch_bounds__(256) void k_gatxh_t(const float* __restrict__ h,
                                                 const float* __restrict__ w,
                                                 const float* __restrict__ att_s,
                                                 const float* __restrict__ att_d,
                                                 ushort* __restrict__ xhb,
                                                 float* __restrict__ a_s,
                                                 float* __restrict__ a_d) {
    __shared__ float As[64][AST];
    __shared__ float Ws[64 * 64];
    int nbase = blockIdx.x * 64;
    int tc = threadIdx.x & 15, tr = threadIdx.x >> 4;
    stageA(h, nbase, HD, 0, As);
#pragma unroll
    for (int half = 0; half < 2; half++) {
        if (half) __syncthreads();
        stageWcols(w, 128, half * 64, Ws);
        __syncthreads();
        float acc[4][4] = {};
        mac16v(As, Ws, acc, tr, tc);
        float as0 = att_s[half * 64 + tc * 4], as1 = att_s[half * 64 + tc * 4 + 1];
        float as2 = att_s[half * 64 + tc * 4 + 2], as3 = att_s[half * 64 + tc * 4 + 3];
        float ad0 = att_d[half * 64 + tc * 4], ad1 = att_d[half * 64 + tc * 4 + 1];
        float ad2 = att_d[half * 64 + tc * 4 + 2], ad3 = att_d[half * 64 + tc * 4 + 3];
#pragma unroll
        for (int i = 0; i < 4; i++) {
            int row = nbase + tr * 4 + i;
            float ps = acc[i][0] * as0 + acc[i][1] * as1 + acc[i][2] * as2 + acc[i][3] * as3;
            float pd = acc[i][0] * ad0 + acc[i][1] * ad1 + acc[i][2] * ad2 + acc[i][3] * ad3;
#pragma unroll
            for (int off = 8; off; off >>= 1) {
                ps += __shfl_xor(ps, off);
                pd += __shfl_xor(pd, off);
            }
            if (row < NN) {
                ushort4 ob = {f2b(acc[i][0]), f2b(acc[i][1]), f2b(acc[i][2]), f2b(acc[i][3])};
                *(ushort4*)&xhb[(size_t)row * 128 + half * 64 + tc * 4] = ob;
                if (tc == 0) {
                    a_s[row * 2 + half] = ps;
                    a_d[row * 2 + half] = pd;
                }
            }
        }
    }
}

// ================= GAT fused (4-edge unroll) =================
__global__ void k_gat_fused(const int* __restrict__ rowptr, const int* __restrict__ colsrc,
                            const float* __restrict__ a_s, const float* __restrict__ a_d,
                            const ushort* __restrict__ xhb, const float* __restrict__ gb,
                            float* __restrict__ hout) {
    int t = threadIdx.x & 63;
    int lane = t & 31, half = t >> 5;
    int bl4 = (lane & 15) * 4;
    float4 bias4 = *(const float4*)&gb[bl4];
    int gw = blockIdx.x * (blockDim.x >> 6) + (threadIdx.x >> 6);
    int stride = gridDim.x * (blockDim.x >> 6);
    for (int n = gw; n < NN; n += stride) {
        int bg = rowptr[n], en = rowptr[n + 1];
        float ad0 = a_d[n * 2], ad1 = a_d[n * 2 + 1];
        float a0 = 0.f, a1 = 0.f, a2 = 0.f, a3 = 0.f;
        float ss0 = 0.f, ss1 = 0.f;
        int i = bg + half;
        for (; i + 6 < en; i += 8) {
            int sa = colsrc[i], sb = colsrc[i + 2], sc = colsrc[i + 4], sd = colsrc[i + 6];
            float2 ava = *(const float2*)&a_s[sa * 2];
            float2 avb = *(const float2*)&a_s[sb * 2];
            float2 avc = *(const float2*)&a_s[sc * 2];
            float2 avd = *(const float2*)&a_s[sd * 2];
            ushort4 xva = *(const ushort4*)&xhb[(size_t)sa * 128 + lane * 4];
            ushort4 xvb = *(const ushort4*)&xhb[(size_t)sb * 128 + lane * 4];
            ushort4 xvc = *(const ushort4*)&xhb[(size_t)sc * 128 + lane * 4];
            ushort4 xvd = *(const ushort4*)&xhb[(size_t)sd * 128 + lane * 4];
            float wa0 = __expf(lrelu(ava.x + ad0)), wa1 = __expf(lrelu(ava.y + ad1));
            float wb0 = __expf(lrelu(avb.x + ad0)), wb1 = __expf(lrelu(avb.y + ad1));
            float wc0 = __expf(lrelu(avc.x + ad0)), wc1 = __expf(lrelu(avc.y + ad1));
            float wd0 = __expf(lrelu(avd.x + ad0)), wd1 = __expf(lrelu(avd.y + ad1));
            ss0 += wa0 + wb0 + wc0 + wd0;
            ss1 += wa1 + wb1 + wc1 + wd1;
            float wsa = (lane < 16) ? wa0 : wa1;
            float wsb = (lane < 16) ? wb0 : wb1;
            float wsc = (lane < 16) ? wc0 : wc1;
            float wsd = (lane < 16) ? wd0 : wd1;
            a0 += wsa * b2f(xva.x) + wsb * b2f(xvb.x) + wsc * b2f(xvc.x) + wsd * b2f(xvd.x);
            a1 += wsa * b2f(xva.y) + wsb * b2f(xvb.y) + wsc * b2f(xvc.y) + wsd * b2f(xvd.y);
            a2 += wsa * b2f(xva.z) + wsb * b2f(xvb.z) + wsc * b2f(xvc.z) + wsd * b2f(xvd.z);
            a3 += wsa * b2f(xva.w) + wsb * b2f(xvb.w) + wsc * b2f(xvc.w) + wsd * b2f(xvd.w);
        }
        for (; i < en; i += 2) {
            int s = colsrc[i];
            float2 av = *(const float2*)&a_s[s * 2];
            float w0 = __expf(lrelu(av.x + ad0));
            float w1 = __expf(lrelu(av.y + ad1));
            ss0 += w0;
            ss1 += w1;
            float wsel = (lane < 16) ? w0 : w1;
            ushort4 xv = *(const ushort4*)&xhb[(size_t)s * 128 + lane * 4];
            a0 += wsel * b2f(xv.x);
            a1 += wsel * b2f(xv.y);
            a2 += wsel * b2f(xv.z);
            a3 += wsel * b2f(xv.w);
        }
        if (half == 0) {  // self-loop
            float2 av = *(const float2*)&a_s[n * 2];
            float w0 = __expf(lrelu(av.x + ad0));
            float w1 = __expf(lrelu(av.y + ad1));
            ss0 += w0;
            ss1 += w1;
            float wsel = (lane < 16) ? w0 : w1;
            ushort4 xv = *(const ushort4*)&xhb[(size_t)n * 128 + lane * 4];
            a0 += wsel * b2f(xv.x);
            a1 += wsel * b2f(xv.y);
            a2 += wsel * b2f(xv.z);
            a3 += wsel * b2f(xv.w);
        }
        ss0 += __shfl_xor(ss0, 32);
        ss1 += __shfl_xor(ss1, 32);
        a0 += __shfl_xor(a0, 32);
        a1 += __shfl_xor(a1, 32);
        a2 += __shfl_xor(a2, 32);
        a3 += __shfl_xor(a3, 32);
        float r = (lane < 16) ? (0.5f / (ss0 + 1e-16f)) : (0.5f / (ss1 + 1e-16f));
        float v0 = a0 * r, v1 = a1 * r, v2 = a2 * r, v3 = a3 * r;
        float p0 = __shfl_xor(v0, 16);
        float p1 = __shfl_xor(v1, 16);
        float p2 = __shfl_xor(v2, 16);
        float p3 = __shfl_xor(v3, 16);
        if (half == 0 && lane < 16) {
            float4 o = {fmaxf(v0 + p0 + bias4.x, 0.f), fmaxf(v1 + p1 + bias4.y, 0.f),
                        fmaxf(v2 + p2 + bias4.z, 0.f), fmaxf(v3 + p3 + bias4.w, 0.f)};
            *(float4*)&hout[(size_t)n * HD + lane * 4] = o;
        }
    }
}

// ================= final SAGE (R12) =================
__global__ void k_pfin(const float* __restrict__ h, const float* __restrict__ wl,
                       ushort* __restrict__ Pb) {
    __shared__ float sw[HD * OUTD];
    for (int i = threadIdx.x; i < HD * OUTD; i += blockDim.x) sw[i] = wl[i];
    __syncthreads();
    int t = threadIdx.x & 63;
    int c = t & 31, half = t >> 5;
    int gw = blockIdx.x * (blockDim.x >> 6) + (threadIdx.x >> 6);
    int stride = gridDim.x * (blockDim.x >> 6);
    for (int n = gw; n < NN; n += stride) {
        float hv = h[(size_t)n * HD + t];
        float acc = 0.f;
#pragma unroll 8
        for (int i = 0; i < 32; i++) {
            float bb = __shfl(hv, half * 32 + i);
            acc += bb * sw[half * 1024 + i * 32 + c];
        }
        acc += __shfl_xor(acc, 32);
        if (half == 0) Pb[(size_t)n * OUTD + c] = f2b(acc);
    }
}

__global__ void k_final_fused(const int* __restrict__ rowptr, const int* __restrict__ colsrc,
                              const float* __restrict__ invdeg, const ushort* __restrict__ Pb,
                              const float* __restrict__ h, const float* __restrict__ bl,
                              const float* __restrict__ wr, float* __restrict__ out) {
    __shared__ float sw[HD * OUTD];
    for (int i = threadIdx.x; i < HD * OUTD; i += blockDim.x) sw[i] = wr[i];
    __syncthreads();
    int t = threadIdx.x & 63;
    int j = t & 31, half = t >> 5;
    int quarter = t >> 4, lane16 = t & 15;
    float bias = bl[j];
    int gw = blockIdx.x * (blockDim.x >> 6) + (threadIdx.x >> 6);
    int stride = gridDim.x * (blockDim.x >> 6);
    for (int n = gw; n < NN; n += stride) {
        int bg = rowptr[n], en = rowptr[n + 1];
        float a0 = 0.f, a1 = 0.f;
        int i = bg + quarter;
        for (; i + 4 < en; i += 8) {
            int sa = colsrc[i], sb = colsrc[i + 4];
            ushort2 va = *(const ushort2*)&Pb[(size_t)sa * OUTD + lane16 * 2];
            ushort2 vb = *(const ushort2*)&Pb[(size_t)sb * OUTD + lane16 * 2];
            a0 += b2f(va.x) + b2f(vb.x);
            a1 += b2f(va.y) + b2f(vb.y);
        }
        for (; i < en; i += 4) {
            int s = colsrc[i];
            ushort2 v = *(const ushort2*)&Pb[(size_t)s * OUTD + lane16 * 2];
            a0 += b2f(v.x);
            a1 += b2f(v.y);
        }
        a0 += __shfl_xor(a0, 32);
        a1 += __shfl_xor(a1, 32);
        a0 += __shfl_xor(a0, 16);
        a1 += __shfl_xor(a1, 16);
        float hv = h[(size_t)n * HD + t];
        float o = 0.f;
#pragma unroll 8
        for (int i2 = 0; i2 < 32; i2++) {
            float bb = __shfl(hv, half * 32 + i2);
            o += bb * sw[half * 1024 + i2 * 32 + j];
        }
        o += __shfl_xor(o, 32);
        float ga = __shfl(a0, j >> 1);
        float gb_ = __shfl(a1, j >> 1);
        float gv = (j & 1) ? gb_ : ga;
        if (half == 0) out[(size_t)n * OUTD + j] = gv * invdeg[n] + bias + o;
    }
}

// ================= launch =================
extern "C" void kernel_launch(void* const* d_in, const int* in_sizes, int n_in,
                              void* d_out, int out_size, void* d_ws, size_t ws_size,
                              hipStream_t stream) {
    const float* x      = (const float*)d_in[0];
    const int*   eidx   = (const int*)d_in[1];
    const float* n2v    = (const float*)d_in[2];
    const float* n2v_w  = (const float*)d_in[3];
    const float* n2v_b  = (const float*)d_in[4];
    const float* ip_w   = (const float*)d_in[5];
    const float* ip_b   = (const float*)d_in[6];
    const float* gate_w = (const float*)d_in[7];
    const float* gate_b = (const float*)d_in[8];
    const float* s0_wl  = (const float*)d_in[9];
    const float* s0_bl  = (const float*)d_in[10];
    const float* s0_wr  = (const float*)d_in[11];
    const float* s1_wl  = (const float*)d_in[12];
    const float* s1_bl  = (const float*)d_in[13];
    const float* s1_wr  = (const float*)d_in[14];
    const float* gat_w  = (const float*)d_in[15];
    const float* att_s  = (const float*)d_in[16];
    const float* att_d  = (const float*)d_in[17];
    const float* gat_b  = (const float*)d_in[18];
    const float* f_wl   = (const float*)d_in[19];
    const float* f_bl   = (const float*)d_in[20];
    const float* f_wr   = (const float*)d_in[21];

    const int* src = eidx;
    const int* dst = eidx + NE;

    // ---- workspace ----
    float*  ws     = (float*)d_ws;
    float*  invdeg = ws;                         // N
    float*  S1     = invdeg + NN;                // 64N  (h1, h3)
    float*  S2     = S1 + (size_t)NN * HD;       // 64N  (h0, h2)
    ushort* aggb   = (ushort*)(S2 + (size_t)NN * HD);   // 64N ushort (bf16 agg)
    float*  a_s    = (float*)(aggb + (size_t)NN * HD);  // 2N
    float*  a_d    = a_s + (size_t)NN * 2;       // 2N
    ushort* Pb     = (ushort*)(a_d + (size_t)NN * 2);   // 32N ushort
    ushort* hb     = Pb + (size_t)NN * OUTD;            // 64N ushort
    ushort* xhb    = hb + (size_t)NN * HD;              // 128N ushort
    int*    cnt    = (int*)(xhb + (size_t)NN * 128);    // N
    int*    rowptr = cnt + NN;                   // N+1
    int*    cursor = rowptr + NN + 1;            // N
    int*    blksum = cursor + NN;                // 128
    int*    colsrc = blksum + 128;               // NE

    float* out = (float*)d_out;

    const int BT = 256;
    dim3 b128(128), b256(BT);
    int eblk = (NE + BT - 1) / BT;
    int nblk = (NN + BT - 1) / BT;

    // ---- CSR prefix ----
    hipMemsetAsync(cnt, 0, (size_t)NN * 4, stream);
    k_count<<<eblk, b256, 0, stream>>>(dst, cnt);
    k_scan1<<<SNBLK, b256, 0, stream>>>(cnt, rowptr, blksum);
    k_scan2<<<1, b128, 0, stream>>>(blksum);
    k_scan3<<<nblk, b256, 0, stream>>>(blksum, cnt, rowptr, cursor, invdeg);

    // ---- mega: CSR fill (first) + front (overlapped) ----
    k_megafront<<<NFILL + NT, b256, 0, stream>>>(x, n2v, n2v_w, n2v_b, ip_w, ip_b,
                                                 gate_w, gate_b, S2, hb,
                                                 src, dst, cursor, colsrc);

    // ---- SAGE 0: S2 -> S1 ----
    k_gather_mean<<<2048, b256, 0, stream>>>(rowptr, colsrc, invdeg, hb, aggb);
    k_sage_t<<<NT, b256, 0, stream>>>(aggb, S2, s0_wl, s0_bl, s0_wr, S1, hb);

    // ---- SAGE 1: S1 -> S2 ----
    k_gather_mean<<<2048, b256, 0, stream>>>(rowptr, colsrc, invdeg, hb, aggb);
    k_sage_t<<<NT, b256, 0, stream>>>(aggb, S1, s1_wl, s1_bl, s1_wr, S2, hb);

    // ---- GAT: S2 -> S1 ----
    k_gatxh_t<<<NT, b256, 0, stream>>>(S2, gat_w, att_s, att_d, xhb, a_s, a_d);
    k_gat_fused<<<2048, b256, 0, stream>>>(rowptr, colsrc, a_s, a_d, xhb, gat_b, S1);

    // ---- final SAGE: S1 -> out ----
    k_pfin<<<2048, b256, 0, stream>>>(S1, f_wl, Pb);
    k_final_fused<<<2048, b256, 0, stream>>>(rowptr, colsrc, invdeg, Pb, S1, f_bl, f_wr, out);
}

// Round 19
// 647.003 us; speedup vs baseline: 1.2960x; 1.0237x over previous
//
#include <hip/hip_runtime.h>
#include <math.h>

#define NN 100000
#define NE 1600000
#define DIN 256
#define HD 64
#define OUTD 32
#define EMBD 128
#define SLOPE 0.2f
#define AST 68
#define NT ((NN + 63) / 64)
#define SCHUNK 1024
#define SNBLK ((NN + SCHUNK - 1) / SCHUNK)   // 98
#define FCH 25000
#define FNC ((NE + FCH - 1) / FCH)           // 64 chunks
#define NFILL (8 * FNC)                      // 512 fill blocks (scheduled FIRST)

typedef __attribute__((ext_vector_type(8))) short bf16x8;
typedef __attribute__((ext_vector_type(8))) unsigned short u16x8;
typedef __attribute__((ext_vector_type(4))) float f32x4;

__device__ __forceinline__ float lrelu(float x) { return x > 0.f ? x : SLOPE * x; }
__device__ __forceinline__ ushort f2b(float f) {
    unsigned u = __float_as_uint(f);
    return (ushort)((u + 0x7FFFu + ((u >> 16) & 1u)) >> 16);  // RTNE fp32->bf16
}
__device__ __forceinline__ float b2f(ushort v) { return __uint_as_float(((unsigned)v) << 16); }

// ================= CSR build =================
__global__ void k_count(const int* __restrict__ dst, int* __restrict__ cnt) {
    int i = blockIdx.x * blockDim.x + threadIdx.x;
    if (i < NE) atomicAdd(&cnt[dst[i]], 1);
}

__global__ __launch_bounds__(256) void k_scan1(const int* __restrict__ cnt,
                                               int* __restrict__ rowptr,
                                               int* __restrict__ blksum) {
    __shared__ int ts[256];
    int base = blockIdx.x * SCHUNK + threadIdx.x * 4;
    int v0 = 0, v1 = 0, v2 = 0, v3 = 0;
    if (base < NN)     v0 = cnt[base];
    if (base + 1 < NN) v1 = cnt[base + 1];
    if (base + 2 < NN) v2 = cnt[base + 2];
    if (base + 3 < NN) v3 = cnt[base + 3];
    int s = v0 + v1 + v2 + v3;
    ts[threadIdx.x] = s;
    __syncthreads();
    for (int off = 1; off < 256; off <<= 1) {
        int w = (threadIdx.x >= off) ? ts[threadIdx.x - off] : 0;
        __syncthreads();
        ts[threadIdx.x] += w;
        __syncthreads();
    }
    int excl = ts[threadIdx.x] - s;
    if (base < NN)     rowptr[base]     = excl;
    if (base + 1 < NN) rowptr[base + 1] = excl + v0;
    if (base + 2 < NN) rowptr[base + 2] = excl + v0 + v1;
    if (base + 3 < NN) rowptr[base + 3] = excl + v0 + v1 + v2;
    if (threadIdx.x == 255) blksum[blockIdx.x] = ts[255];
}

__global__ __launch_bounds__(128) void k_scan2(int* __restrict__ blksum) {
    __shared__ int ts[128];
    int t = threadIdx.x;
    int v = (t < SNBLK) ? blksum[t] : 0;
    ts[t] = v;
    __syncthreads();
    for (int off = 1; off < 128; off <<= 1) {
        int w = (t >= off) ? ts[t - off] : 0;
        __syncthreads();
        ts[t] += w;
        __syncthreads();
    }
    if (t < SNBLK) blksum[t] = ts[t] - v;
}

__global__ void k_scan3(const int* __restrict__ blksum, const int* __restrict__ cnt,
                        int* __restrict__ rowptr, int* __restrict__ cursor,
                        float* __restrict__ invdeg) {
    int i = blockIdx.x * blockDim.x + threadIdx.x;
    if (i < NN) {
        int v = rowptr[i] + blksum[i >> 10];
        rowptr[i] = v;
        cursor[i] = v;
        invdeg[i] = 1.0f / fmaxf((float)cnt[i], 1.0f);
    }
    if (i == 0) rowptr[NN] = NE;
}

// ================= fp32 tiled GEMM helpers =================
__device__ __forceinline__ void stageA(const float* __restrict__ g, int nbase, int ldg, int koff,
                                       float (*As)[AST]) {
    for (int i = threadIdx.x; i < 1024; i += 256) {
        int m = i >> 4, k4 = (i & 15) << 2;
        int row = nbase + m;
        if (row >= NN) row = NN - 1;
        *(float4*)&As[m][k4] = *(const float4*)&g[(size_t)row * ldg + koff + k4];
    }
}
__device__ __forceinline__ void stageAb(const ushort* __restrict__ g, int nbase, int ldg,
                                        float (*As)[AST]) {
    for (int i = threadIdx.x; i < 1024; i += 256) {
        int m = i >> 4, k4 = (i & 15) << 2;
        int row = nbase + m;
        if (row >= NN) row = NN - 1;
        ushort4 v = *(const ushort4*)&g[(size_t)row * ldg + k4];
        As[m][k4] = b2f(v.x); As[m][k4 + 1] = b2f(v.y);
        As[m][k4 + 2] = b2f(v.z); As[m][k4 + 3] = b2f(v.w);
    }
}
__device__ __forceinline__ void stageW(const float* __restrict__ g, float* Ws) {
    for (int i = threadIdx.x; i < 1024; i += 256) ((float4*)Ws)[i] = ((const float4*)g)[i];
}
__device__ __forceinline__ void stageWcols(const float* __restrict__ g, int ldg, int coff,
                                           float* Ws) {
    for (int i = threadIdx.x; i < 1024; i += 256) {
        int r = i >> 4, c4 = (i & 15) << 2;
        *(float4*)&Ws[r * 64 + c4] = *(const float4*)&g[r * ldg + coff + c4];
    }
}
__device__ __forceinline__ void mac16v(const float (*As)[AST], const float* __restrict__ Ws,
                                       float (*acc)[4], int tr, int tc) {
#pragma unroll 4
    for (int k4 = 0; k4 < 64; k4 += 4) {
        float4 a0 = *(const float4*)&As[tr * 4 + 0][k4];
        float4 a1 = *(const float4*)&As[tr * 4 + 1][k4];
        float4 a2 = *(const float4*)&As[tr * 4 + 2][k4];
        float4 a3 = *(const float4*)&As[tr * 4 + 3][k4];
#pragma unroll
        for (int j = 0; j < 4; j++) {
            float4 w = *(const float4*)&Ws[(k4 + j) * 64 + tc * 4];
            float e0 = (&a0.x)[j], e1 = (&a1.x)[j], e2 = (&a2.x)[j], e3 = (&a3.x)[j];
            acc[0][0] += e0 * w.x; acc[0][1] += e0 * w.y; acc[0][2] += e0 * w.z; acc[0][3] += e0 * w.w;
            acc[1][0] += e1 * w.x; acc[1][1] += e1 * w.y; acc[1][2] += e1 * w.z; acc[1][3] += e1 * w.w;
            acc[2][0] += e2 * w.x; acc[2][1] += e2 * w.y; acc[2][2] += e2 * w.z; acc[2][3] += e2 * w.w;
            acc[3][0] += e3 * w.x; acc[3][1] += e3 * w.y; acc[3][2] += e3 * w.z; acc[3][3] += e3 * w.w;
        }
    }
}

// ================= mega-front: fill blocks FIRST, then MFMA front blocks =================
__global__ __launch_bounds__(256) void k_megafront(
        const float* __restrict__ x, const float* __restrict__ n2v,
        const float* __restrict__ n2v_w, const float* __restrict__ n2v_b,
        const float* __restrict__ ip_w, const float* __restrict__ ip_b,
        const float* __restrict__ gate_w, const float* __restrict__ gate_b,
        float* __restrict__ h0, ushort* __restrict__ h0b,
        const int* __restrict__ esrc, const int* __restrict__ edst,
        int* __restrict__ cursor, int* __restrict__ colsrc) {
    __shared__ ushort Ah[64][40], Al[64][40];
    __shared__ ushort Bih[64][40], Bil[64][40];
    __shared__ ushort Bgh[64][40], Bgl[64][40];

    if (blockIdx.x < NFILL) {
        int cls = blockIdx.x & 7;
        int chunk = blockIdx.x >> 3;
        int lo = cls * (NN / 8);
        int hi = (cls == 7) ? NN : lo + (NN / 8);
        int beg = chunk * FCH;
        int end = min(beg + FCH, NE);
        for (int i = beg + (int)threadIdx.x; i < end; i += 256) {
            int d = edst[i];
            if (d >= lo && d < hi) {
                int pos = atomicAdd(&cursor[d], 1);
                colsrc[pos] = esrc[i];
            }
        }
        return;
    }

    int nbase = (blockIdx.x - NFILL) * 64;
    int tid = threadIdx.x;
    int w = tid >> 6, l = tid & 63;
    int lr = l & 15, lg = l >> 4, lk = lg * 8;
    f32x4 zero = {0.f, 0.f, 0.f, 0.f};
    f32x4 araw[4], ag[4], adel[4], pn[4];
#pragma unroll
    for (int t = 0; t < 4; t++) { araw[t] = zero; ag[t] = zero; adel[t] = zero; pn[t] = zero; }

    int arow = tid >> 2, ak0 = (tid & 3) << 3;
    int garow = nbase + arow;
    if (garow >= NN) garow = NN - 1;

    // --- phase 0: n2vp ---
    for (int c = 0; c < 4; c++) {
        if (c) __syncthreads();
        {
            const float* ap = &n2v[(size_t)garow * EMBD + c * 32 + ak0];
            u16x8 th, tl;
#pragma unroll
            for (int u = 0; u < 8; u++) {
                float v = ap[u];
                ushort h = f2b(v);
                th[u] = h;
                tl[u] = f2b(v - b2f(h));
            }
            *(u16x8*)&Ah[arow][ak0] = th;
            *(u16x8*)&Al[arow][ak0] = tl;
        }
        {
            const float* pw = &n2v_w[(size_t)(c * 32 + w * 8) * 64 + l];
            u16x8 ih, il;
#pragma unroll
            for (int u = 0; u < 8; u++) {
                float v = pw[u * 64];
                ushort h = f2b(v);
                ih[u] = h;
                il[u] = f2b(v - b2f(h));
            }
            *(u16x8*)&Bih[l][w * 8] = ih;
            *(u16x8*)&Bil[l][w * 8] = il;
        }
        __syncthreads();
        bf16x8 ah = *(const bf16x8*)&Ah[w * 16 + lr][lk];
        bf16x8 al = *(const bf16x8*)&Al[w * 16 + lr][lk];
#pragma unroll
        for (int t = 0; t < 4; t++) {
            int col = t * 16 + lr;
            bf16x8 bih = *(const bf16x8*)&Bih[col][lk];
            bf16x8 bil = *(const bf16x8*)&Bil[col][lk];
            f32x4 r = pn[t];
            r = __builtin_amdgcn_mfma_f32_16x16x32_bf16(ah, bih, r, 0, 0, 0);
            r = __builtin_amdgcn_mfma_f32_16x16x32_bf16(ah, bil, r, 0, 0, 0);
            r = __builtin_amdgcn_mfma_f32_16x16x32_bf16(al, bih, r, 0, 0, 0);
            pn[t] = r;
        }
    }
#pragma unroll
    for (int t = 0; t < 4; t++) {
        float nb = n2v_b[t * 16 + lr];
#pragma unroll
        for (int r = 0; r < 4; r++) pn[t][r] += nb;
    }

    // --- phase 1: x chunks ---
    for (int c = 0; c < 8; c++) {
        __syncthreads();
        {
            const float* ap = &x[(size_t)garow * DIN + c * 32 + ak0];
            u16x8 th, tl;
#pragma unroll
            for (int u = 0; u < 8; u++) {
                float v = ap[u];
                ushort h = f2b(v);
                th[u] = h;
                tl[u] = f2b(v - b2f(h));
            }
            *(u16x8*)&Ah[arow][ak0] = th;
            *(u16x8*)&Al[arow][ak0] = tl;
        }
        {
            const float* pi = &ip_w[(size_t)(c * 32 + w * 8) * 64 + l];
            const float* pg = &gate_w[(size_t)(c * 32 + w * 8) * 64 + l];
            u16x8 ih, il, gh, gl2;
#pragma unroll
            for (int u = 0; u < 8; u++) {
                float v = pi[u * 64];
                ushort h = f2b(v);
                ih[u] = h; il[u] = f2b(v - b2f(h));
                float g = pg[u * 64];
                ushort hg = f2b(g);
                gh[u] = hg; gl2[u] = f2b(g - b2f(hg));
            }
            *(u16x8*)&Bih[l][w * 8] = ih;
            *(u16x8*)&Bil[l][w * 8] = il;
            *(u16x8*)&Bgh[l][w * 8] = gh;
            *(u16x8*)&Bgl[l][w * 8] = gl2;
        }
        __syncthreads();
        bf16x8 ah = *(const bf16x8*)&Ah[w * 16 + lr][lk];
        bf16x8 al = *(const bf16x8*)&Al[w * 16 + lr][lk];
#pragma unroll
        for (int t = 0; t < 4; t++) {
            int col = t * 16 + lr;
            bf16x8 bih = *(const bf16x8*)&Bih[col][lk];
            bf16x8 bil = *(const bf16x8*)&Bil[col][lk];
            bf16x8 bgh = *(const bf16x8*)&Bgh[col][lk];
            bf16x8 bgl = *(const bf16x8*)&Bgl[col][lk];
            f32x4 r = araw[t];
            r = __builtin_amdgcn_mfma_f32_16x16x32_bf16(ah, bih, r, 0, 0, 0);
            r = __builtin_amdgcn_mfma_f32_16x16x32_bf16(ah, bil, r, 0, 0, 0);
            r = __builtin_amdgcn_mfma_f32_16x16x32_bf16(al, bih, r, 0, 0, 0);
            araw[t] = r;
            f32x4 g = ag[t];
            g = __builtin_amdgcn_mfma_f32_16x16x32_bf16(ah, bgh, g, 0, 0, 0);
            g = __builtin_amdgcn_mfma_f32_16x16x32_bf16(ah, bgl, g, 0, 0, 0);
            g = __builtin_amdgcn_mfma_f32_16x16x32_bf16(al, bgh, g, 0, 0, 0);
            ag[t] = g;
        }
    }

    // --- phase 2: pn tail chunks ---
    for (int c = 0; c < 2; c++) {
        __syncthreads();
#pragma unroll
        for (int tt = 0; tt < 2; tt++) {
            int t = c * 2 + tt;
            int ak = tt * 16 + lr;
#pragma unroll
            for (int r = 0; r < 4; r++) {
                int row = w * 16 + lg * 4 + r;
                float v = pn[t][r];
                ushort h = f2b(v);
                Ah[row][ak] = h;
                Al[row][ak] = f2b(v - b2f(h));
            }
        }
        {
            const float* pi = &ip_w[(size_t)(DIN + c * 32 + w * 8) * 64 + l];
            const float* pg = &gate_w[(size_t)(DIN + c * 32 + w * 8) * 64 + l];
            u16x8 ih, il, gh, gl2;
#pragma unroll
            for (int u = 0; u < 8; u++) {
                float v = pi[u * 64];
                ushort h = f2b(v);
                ih[u] = h; il[u] = f2b(v - b2f(h));
                float g = pg[u * 64];
                ushort hg = f2b(g);
                gh[u] = hg; gl2[u] = f2b(g - b2f(hg));
            }
            *(u16x8*)&Bih[l][w * 8] = ih;
            *(u16x8*)&Bil[l][w * 8] = il;
            *(u16x8*)&Bgh[l][w * 8] = gh;
            *(u16x8*)&Bgl[l][w * 8] = gl2;
        }
        __syncthreads();
        bf16x8 ah = *(const bf16x8*)&Ah[w * 16 + lr][lk];
        bf16x8 al = *(const bf16x8*)&Al[w * 16 + lr][lk];
#pragma unroll
        for (int t = 0; t < 4; t++) {
            int col = t * 16 + lr;
            bf16x8 bih = *(const bf16x8*)&Bih[col][lk];
            bf16x8 bil = *(const bf16x8*)&Bil[col][lk];
            bf16x8 bgh = *(const bf16x8*)&Bgh[col][lk];
            bf16x8 bgl = *(const bf16x8*)&Bgl[col][lk];
            f32x4 r = adel[t];
            r = __builtin_amdgcn_mfma_f32_16x16x32_bf16(ah, bih, r, 0, 0, 0);
            r = __builtin_amdgcn_mfma_f32_16x16x32_bf16(ah, bil, r, 0, 0, 0);
            r = __builtin_amdgcn_mfma_f32_16x16x32_bf16(al, bih, r, 0, 0, 0);
            adel[t] = r;
            f32x4 g = ag[t];
            g = __builtin_amdgcn_mfma_f32_16x16x32_bf16(ah, bgh, g, 0, 0, 0);
            g = __builtin_amdgcn_mfma_f32_16x16x32_bf16(ah, bgl, g, 0, 0, 0);
            g = __builtin_amdgcn_mfma_f32_16x16x32_bf16(al, bgh, g, 0, 0, 0);
            ag[t] = g;
        }
    }
#pragma unroll
    for (int t = 0; t < 4; t++) {
        int col = t * 16 + lr;
        float ib = ip_b[col], gb2 = gate_b[col];
#pragma unroll
        for (int r = 0; r < 4; r++) {
            int row = nbase + w * 16 + lg * 4 + r;
            if (row < NN) {
                float raw = araw[t][r] + ib;
                float sg = 1.f / (1.f + __expf(-(ag[t][r] + gb2)));
                float o = raw + sg * adel[t][r];
                h0[(size_t)row * HD + col] = o;
                h0b[(size_t)row * HD + col] = f2b(o);
            }
        }
    }
}

// ================= gather mean: quarter-wave/edge, ushort4/lane, 2-edge unroll ============
__global__ void k_gather_mean(const int* __restrict__ rowptr, const int* __restrict__ colsrc,
                              const float* __restrict__ invdeg, const ushort* __restrict__ hb,
                              ushort* __restrict__ aggb) {
    int t = threadIdx.x & 63;
    int lane16 = t & 15, quarter = t >> 4;
    int gw = blockIdx.x * (blockDim.x >> 6) + (threadIdx.x >> 6);
    int stride = gridDim.x * (blockDim.x >> 6);
    for (int n = gw; n < NN; n += stride) {
        int bg = rowptr[n], en = rowptr[n + 1];
        float a0 = 0.f, a1 = 0.f, a2 = 0.f, a3 = 0.f;
        int i = bg + quarter;
        for (; i + 4 < en; i += 8) {
            int sa = colsrc[i], sb = colsrc[i + 4];
            ushort4 va = *(const ushort4*)&hb[(size_t)sa * HD + lane16 * 4];
            ushort4 vb = *(const ushort4*)&hb[(size_t)sb * HD + lane16 * 4];
            a0 += b2f(va.x) + b2f(vb.x);
            a1 += b2f(va.y) + b2f(vb.y);
            a2 += b2f(va.z) + b2f(vb.z);
            a3 += b2f(va.w) + b2f(vb.w);
        }
        for (; i < en; i += 4) {
            int s = colsrc[i];
            ushort4 v = *(const ushort4*)&hb[(size_t)s * HD + lane16 * 4];
            a0 += b2f(v.x);
            a1 += b2f(v.y);
            a2 += b2f(v.z);
            a3 += b2f(v.w);
        }
        a0 += __shfl_xor(a0, 32); a1 += __shfl_xor(a1, 32);
        a2 += __shfl_xor(a2, 32); a3 += __shfl_xor(a3, 32);
        a0 += __shfl_xor(a0, 16); a1 += __shfl_xor(a1, 16);
        a2 += __shfl_xor(a2, 16); a3 += __shfl_xor(a3, 16);
        if (quarter == 0) {
            float id = invdeg[n];
            ushort4 o = {f2b(a0 * id), f2b(a1 * id), f2b(a2 * id), f2b(a3 * id)};
            *(ushort4*)&aggb[(size_t)n * HD + lane16 * 4] = o;
        }
    }
}

// ================= SAGE combine (bf16 agg in) =================
__global__ __launch_bounds__(256) void k_sage_t(const ushort* __restrict__ aggb,
                                                const float* __restrict__ h,
                                                const float* __restrict__ wl,
                                                const float* __restrict__ bl,
                                                const float* __restrict__ wr,
                                                float* __restrict__ hout,
                                                ushort* __restrict__ houtb) {
    __shared__ float As[64][AST];
    __shared__ float Ws[64 * 64];
    int nbase = blockIdx.x * 64;
    int tc = threadIdx.x & 15, tr = threadIdx.x >> 4;
    float acc[4][4] = {};
    stageAb(aggb, nbase, HD, As);
    stageW(wl, Ws);
    __syncthreads();
    mac16v(As, Ws, acc, tr, tc);
    __syncthreads();
    stageA(h, nbase, HD, 0, As);
    stageW(wr, Ws);
    __syncthreads();
    mac16v(As, Ws, acc, tr, tc);
    float b0 = bl[tc * 4], b1 = bl[tc * 4 + 1], b2 = bl[tc * 4 + 2], b3 = bl[tc * 4 + 3];
#pragma unroll
    for (int i = 0; i < 4; i++) {
        int row = nbase + tr * 4 + i;
        if (row < NN) {
            float4 o = {fmaxf(acc[i][0] + b0, 0.f), fmaxf(acc[i][1] + b1, 0.f),
                        fmaxf(acc[i][2] + b2, 0.f), fmaxf(acc[i][3] + b3, 0.f)};
            *(float4*)&hout[(size_t)row * HD + tc * 4] = o;
            ushort4 ob = {f2b(o.x), f2b(o.y), f2b(o.z), f2b(o.w)};
            *(ushort4*)&houtb[(size_t)row * HD + tc * 4] = ob;
        }
    }
}

// ================= GAT transform =================
__global__ __launch_bounds__(256) void k_gatxh_t(const float* __restrict__ h,
                                                 const float* __restrict__ w,
                                                 const float* __restrict__ att_s,
                                                 const float* __restrict__ att_d,
                                                 ushort* __restrict__ xhb,
                                                 float* __restrict__ a_s,
                                                 float* __restrict__ a_d) {
    __shared__ float As[64][AST];
    __shared__ float Ws[64 * 64];
    int nbase = blockIdx.x * 64;
    int tc = threadIdx.x & 15, tr = threadIdx.x >> 4;
    stageA(h, nbase, HD, 0, As);
#pragma unroll
    for (int half = 0; half < 2; half++) {
        if (half) __syncthreads();
        stageWcols(w, 128, half * 64, Ws);
        __syncthreads();
        float acc[4][4] = {};
        mac16v(As, Ws, acc, tr, tc);
        float as0 = att_s[half * 64 + tc * 4], as1 = att_s[half * 64 + tc * 4 + 1];
        float as2 = att_s[half * 64 + tc * 4 + 2], as3 = att_s[half * 64 + tc * 4 + 3];
        float ad0 = att_d[half * 64 + tc * 4], ad1 = att_d[half * 64 + tc * 4 + 1];
        float ad2 = att_d[half * 64 + tc * 4 + 2], ad3 = att_d[half * 64 + tc * 4 + 3];
#pragma unroll
        for (int i = 0; i < 4; i++) {
            int row = nbase + tr * 4 + i;
            float ps = acc[i][0] * as0 + acc[i][1] * as1 + acc[i][2] * as2 + acc[i][3] * as3;
            float pd = acc[i][0] * ad0 + acc[i][1] * ad1 + acc[i][2] * ad2 + acc[i][3] * ad3;
#pragma unroll
            for (int off = 8; off; off >>= 1) {
                ps += __shfl_xor(ps, off);
                pd += __shfl_xor(pd, off);
            }
            if (row < NN) {
                ushort4 ob = {f2b(acc[i][0]), f2b(acc[i][1]), f2b(acc[i][2]), f2b(acc[i][3])};
                *(ushort4*)&xhb[(size_t)row * 128 + half * 64 + tc * 4] = ob;
                if (tc == 0) {
                    a_s[row * 2 + half] = ps;
                    a_d[row * 2 + half] = pd;
                }
            }
        }
    }
}

// ================= GAT fused (4-edge unroll) =================
__global__ void k_gat_fused(const int* __restrict__ rowptr, const int* __restrict__ colsrc,
                            const float* __restrict__ a_s, const float* __restrict__ a_d,
                            const ushort* __restrict__ xhb, const float* __restrict__ gb,
                            float* __restrict__ hout) {
    int t = threadIdx.x & 63;
    int lane = t & 31, half = t >> 5;
    int bl4 = (lane & 15) * 4;
    float4 bias4 = *(const float4*)&gb[bl4];
    int gw = blockIdx.x * (blockDim.x >> 6) + (threadIdx.x >> 6);
    int stride = gridDim.x * (blockDim.x >> 6);
    for (int n = gw; n < NN; n += stride) {
        int bg = rowptr[n], en = rowptr[n + 1];
        float ad0 = a_d[n * 2], ad1 = a_d[n * 2 + 1];
        float a0 = 0.f, a1 = 0.f, a2 = 0.f, a3 = 0.f;
        float ss0 = 0.f, ss1 = 0.f;
        int i = bg + half;
        for (; i + 6 < en; i += 8) {
            int sa = colsrc[i], sb = colsrc[i + 2], sc = colsrc[i + 4], sd = colsrc[i + 6];
            float2 ava = *(const float2*)&a_s[sa * 2];
            float2 avb = *(const float2*)&a_s[sb * 2];
            float2 avc = *(const float2*)&a_s[sc * 2];
            float2 avd = *(const float2*)&a_s[sd * 2];
            ushort4 xva = *(const ushort4*)&xhb[(size_t)sa * 128 + lane * 4];
            ushort4 xvb = *(const ushort4*)&xhb[(size_t)sb * 128 + lane * 4];
            ushort4 xvc = *(const ushort4*)&xhb[(size_t)sc * 128 + lane * 4];
            ushort4 xvd = *(const ushort4*)&xhb[(size_t)sd * 128 + lane * 4];
            float wa0 = __expf(lrelu(ava.x + ad0)), wa1 = __expf(lrelu(ava.y + ad1));
            float wb0 = __expf(lrelu(avb.x + ad0)), wb1 = __expf(lrelu(avb.y + ad1));
            float wc0 = __expf(lrelu(avc.x + ad0)), wc1 = __expf(lrelu(avc.y + ad1));
            float wd0 = __expf(lrelu(avd.x + ad0)), wd1 = __expf(lrelu(avd.y + ad1));
            ss0 += wa0 + wb0 + wc0 + wd0;
            ss1 += wa1 + wb1 + wc1 + wd1;
            float wsa = (lane < 16) ? wa0 : wa1;
            float wsb = (lane < 16) ? wb0 : wb1;
            float wsc = (lane < 16) ? wc0 : wc1;
            float wsd = (lane < 16) ? wd0 : wd1;
            a0 += wsa * b2f(xva.x) + wsb * b2f(xvb.x) + wsc * b2f(xvc.x) + wsd * b2f(xvd.x);
            a1 += wsa * b2f(xva.y) + wsb * b2f(xvb.y) + wsc * b2f(xvc.y) + wsd * b2f(xvd.y);
            a2 += wsa * b2f(xva.z) + wsb * b2f(xvb.z) + wsc * b2f(xvc.z) + wsd * b2f(xvd.z);
            a3 += wsa * b2f(xva.w) + wsb * b2f(xvb.w) + wsc * b2f(xvc.w) + wsd * b2f(xvd.w);
        }
        for (; i < en; i += 2) {
            int s = colsrc[i];
            float2 av = *(const float2*)&a_s[s * 2];
            float w0 = __expf(lrelu(av.x + ad0));
            float w1 = __expf(lrelu(av.y + ad1));
            ss0 += w0;
            ss1 += w1;
            float wsel = (lane < 16) ? w0 : w1;
            ushort4 xv = *(const ushort4*)&xhb[(size_t)s * 128 + lane * 4];
            a0 += wsel * b2f(xv.x);
            a1 += wsel * b2f(xv.y);
            a2 += wsel * b2f(xv.z);
            a3 += wsel * b2f(xv.w);
        }
        if (half == 0) {
            float2 av = *(const float2*)&a_s[n * 2];
            float w0 = __expf(lrelu(av.x + ad0));
            float w1 = __expf(lrelu(av.y + ad1));
            ss0 += w0;
            ss1 += w1;
            float wsel = (lane < 16) ? w0 : w1;
            ushort4 xv = *(const ushort4*)&xhb[(size_t)n * 128 + lane * 4];
            a0 += wsel * b2f(xv.x);
            a1 += wsel * b2f(xv.y);
            a2 += wsel * b2f(xv.z);
            a3 += wsel * b2f(xv.w);
        }
        ss0 += __shfl_xor(ss0, 32);
        ss1 += __shfl_xor(ss1, 32);
        a0 += __shfl_xor(a0, 32);
        a1 += __shfl_xor(a1, 32);
        a2 += __shfl_xor(a2, 32);
        a3 += __shfl_xor(a3, 32);
        float r = (lane < 16) ? (0.5f / (ss0 + 1e-16f)) : (0.5f / (ss1 + 1e-16f));
        float v0 = a0 * r, v1 = a1 * r, v2 = a2 * r, v3 = a3 * r;
        float p0 = __shfl_xor(v0, 16);
        float p1 = __shfl_xor(v1, 16);
        float p2 = __shfl_xor(v2, 16);
        float p3 = __shfl_xor(v3, 16);
        if (half == 0 && lane < 16) {
            float4 o = {fmaxf(v0 + p0 + bias4.x, 0.f), fmaxf(v1 + p1 + bias4.y, 0.f),
                        fmaxf(v2 + p2 + bias4.z, 0.f), fmaxf(v3 + p3 + bias4.w, 0.f)};
            *(float4*)&hout[(size_t)n * HD + lane * 4] = o;
        }
    }
}

// ================= final SAGE =================
__global__ void k_pfin(const float* __restrict__ h, const float* __restrict__ wl,
                       ushort* __restrict__ Pb) {
    __shared__ float sw[HD * OUTD];
    for (int i = threadIdx.x; i < HD * OUTD; i += blockDim.x) sw[i] = wl[i];
    __syncthreads();
    int t = threadIdx.x & 63;
    int c = t & 31, half = t >> 5;
    int gw = blockIdx.x * (blockDim.x >> 6) + (threadIdx.x >> 6);
    int stride = gridDim.x * (blockDim.x >> 6);
    for (int n = gw; n < NN; n += stride) {
        float hv = h[(size_t)n * HD + t];
        float acc = 0.f;
#pragma unroll 8
        for (int i = 0; i < 32; i++) {
            float bb = __shfl(hv, half * 32 + i);
            acc += bb * sw[half * 1024 + i * 32 + c];
        }
        acc += __shfl_xor(acc, 32);
        if (half == 0) Pb[(size_t)n * OUTD + c] = f2b(acc);
    }
}

__global__ void k_final_fused(const int* __restrict__ rowptr, const int* __restrict__ colsrc,
                              const float* __restrict__ invdeg, const ushort* __restrict__ Pb,
                              const float* __restrict__ h, const float* __restrict__ bl,
                              const float* __restrict__ wr, float* __restrict__ out) {
    __shared__ float sw[HD * OUTD];
    for (int i = threadIdx.x; i < HD * OUTD; i += blockDim.x) sw[i] = wr[i];
    __syncthreads();
    int t = threadIdx.x & 63;
    int j = t & 31, half = t >> 5;
    int quarter = t >> 4, lane16 = t & 15;
    float bias = bl[j];
    int gw = blockIdx.x * (blockDim.x >> 6) + (threadIdx.x >> 6);
    int stride = gridDim.x * (blockDim.x >> 6);
    for (int n = gw; n < NN; n += stride) {
        int bg = rowptr[n], en = rowptr[n + 1];
        float a0 = 0.f, a1 = 0.f;
        int i = bg + quarter;
        for (; i + 4 < en; i += 8) {
            int sa = colsrc[i], sb = colsrc[i + 4];
            ushort2 va = *(const ushort2*)&Pb[(size_t)sa * OUTD + lane16 * 2];
            ushort2 vb = *(const ushort2*)&Pb[(size_t)sb * OUTD + lane16 * 2];
            a0 += b2f(va.x) + b2f(vb.x);
            a1 += b2f(va.y) + b2f(vb.y);
        }
        for (; i < en; i += 4) {
            int s = colsrc[i];
            ushort2 v = *(const ushort2*)&Pb[(size_t)s * OUTD + lane16 * 2];
            a0 += b2f(v.x);
            a1 += b2f(v.y);
        }
        a0 += __shfl_xor(a0, 32);
        a1 += __shfl_xor(a1, 32);
        a0 += __shfl_xor(a0, 16);
        a1 += __shfl_xor(a1, 16);
        float hv = h[(size_t)n * HD + t];
        float o = 0.f;
#pragma unroll 8
        for (int i2 = 0; i2 < 32; i2++) {
            float bb = __shfl(hv, half * 32 + i2);
            o += bb * sw[half * 1024 + i2 * 32 + j];
        }
        o += __shfl_xor(o, 32);
        float ga = __shfl(a0, j >> 1);
        float gb_ = __shfl(a1, j >> 1);
        float gv = (j & 1) ? gb_ : ga;
        if (half == 0) out[(size_t)n * OUTD + j] = gv * invdeg[n] + bias + o;
    }
}

// ================= launch =================
extern "C" void kernel_launch(void* const* d_in, const int* in_sizes, int n_in,
                              void* d_out, int out_size, void* d_ws, size_t ws_size,
                              hipStream_t stream) {
    const float* x      = (const float*)d_in[0];
    const int*   eidx   = (const int*)d_in[1];
    const float* n2v    = (const float*)d_in[2];
    const float* n2v_w  = (const float*)d_in[3];
    const float* n2v_b  = (const float*)d_in[4];
    const float* ip_w   = (const float*)d_in[5];
    const float* ip_b   = (const float*)d_in[6];
    const float* gate_w = (const float*)d_in[7];
    const float* gate_b = (const float*)d_in[8];
    const float* s0_wl  = (const float*)d_in[9];
    const float* s0_bl  = (const float*)d_in[10];
    const float* s0_wr  = (const float*)d_in[11];
    const float* s1_wl  = (const float*)d_in[12];
    const float* s1_bl  = (const float*)d_in[13];
    const float* s1_wr  = (const float*)d_in[14];
    const float* gat_w  = (const float*)d_in[15];
    const float* att_s  = (const float*)d_in[16];
    const float* att_d  = (const float*)d_in[17];
    const float* gat_b  = (const float*)d_in[18];
    const float* f_wl   = (const float*)d_in[19];
    const float* f_bl   = (const float*)d_in[20];
    const float* f_wr   = (const float*)d_in[21];

    const int* src = eidx;
    const int* dst = eidx + NE;

    // ---- workspace ----
    float*  ws     = (float*)d_ws;
    float*  invdeg = ws;                         // N
    float*  S1     = invdeg + NN;                // 64N  (h1, h3)
    float*  S2     = S1 + (size_t)NN * HD;       // 64N  (h0, h2)
    ushort* aggb   = (ushort*)(S2 + (size_t)NN * HD);   // 64N ushort (bf16 agg)
    float*  a_s    = (float*)(aggb + (size_t)NN * HD);  // 2N
    float*  a_d    = a_s + (size_t)NN * 2;       // 2N
    ushort* Pb     = (ushort*)(a_d + (size_t)NN * 2);   // 32N ushort
    ushort* hb     = Pb + (size_t)NN * OUTD;            // 64N ushort
    ushort* xhb    = hb + (size_t)NN * HD;              // 128N ushort
    int*    cnt    = (int*)(xhb + (size_t)NN * 128);    // N
    int*    rowptr = cnt + NN;                   // N+1
    int*    cursor = rowptr + NN + 1;            // N
    int*    blksum = cursor + NN;                // 128
    int*    colsrc = blksum + 128;               // NE

    float* out = (float*)d_out;

    const int BT = 256;
    dim3 b128(128), b256(BT);
    int eblk = (NE + BT - 1) / BT;
    int nblk = (NN + BT - 1) / BT;

    // ---- CSR prefix ----
    hipMemsetAsync(cnt, 0, (size_t)NN * 4, stream);
    k_count<<<eblk, b256, 0, stream>>>(dst, cnt);
    k_scan1<<<SNBLK, b256, 0, stream>>>(cnt, rowptr, blksum);
    k_scan2<<<1, b128, 0, stream>>>(blksum);
    k_scan3<<<nblk, b256, 0, stream>>>(blksum, cnt, rowptr, cursor, invdeg);

    // ---- mega: CSR fill (first) + front (overlapped) ----
    k_megafront<<<NFILL + NT, b256, 0, stream>>>(x, n2v, n2v_w, n2v_b, ip_w, ip_b,
                                                 gate_w, gate_b, S2, hb,
                                                 src, dst, cursor, colsrc);

    // ---- SAGE 0: S2 -> S1 ----
    k_gather_mean<<<2048, b256, 0, stream>>>(rowptr, colsrc, invdeg, hb, aggb);
    k_sage_t<<<NT, b256, 0, stream>>>(aggb, S2, s0_wl, s0_bl, s0_wr, S1, hb);

    // ---- SAGE 1: S1 -> S2 ----
    k_gather_mean<<<2048, b256, 0, stream>>>(rowptr, colsrc, invdeg, hb, aggb);
    k_sage_t<<<NT, b256, 0, stream>>>(aggb, S1, s1_wl, s1_bl, s1_wr, S2, hb);

    // ---- GAT: S2 -> S1 ----
    k_gatxh_t<<<NT, b256, 0, stream>>>(S2, gat_w, att_s, att_d, xhb, a_s, a_d);
    k_gat_fused<<<2048, b256, 0, stream>>>(rowptr, colsrc, a_s, a_d, xhb, gat_b, S1);

    // ---- final SAGE: S1 -> out ----
    k_pfin<<<2048, b256, 0, stream>>>(S1, f_wl, Pb);
    k_final_fused<<<2048, b256, 0, stream>>>(rowptr, colsrc, invdeg, Pb, S1, f_bl, f_wr, out);
}